// Round 1
// 536.625 us; speedup vs baseline: 1.6184x; 1.6184x over previous
//
#include <hip/hip_runtime.h>
#include <cstdint>
#include <cstddef>

#define DEVFN __device__ __forceinline__

typedef short bf16x8 __attribute__((ext_vector_type(8)));
typedef float f32x4  __attribute__((ext_vector_type(4)));
typedef int   i32x4  __attribute__((ext_vector_type(4)));

// problem constants
static constexpr int NTOK  = 64 * 196;   // 12544  (= 98 * 128)
static constexpr int DMODEL= 768;
static constexpr int NHEAD = 12;
static constexpr int NQKV  = 2304;       // 3*768 (= 18 * 128)
static constexpr int MMLP  = 3072;       // 4*768 (= 24 * 128)
static constexpr int SEQ   = 196;
static constexpr int NBATCH= 64;

// scale slots (absmax bits, atomicMax on uint reinterpretation of fp32)
enum { SL_LN1=0, SL_WQKV=1, SL_CTX=2, SL_WO=3, SL_LN2=4, SL_W1=5, SL_GELU=6, SL_W2=7 };

// ---- scattered absmax slots: 64 shadow copies per logical slot, 256B apart ----
// Single-address atomicMax serializes at ~11ns/op at the L2 coherence point;
// 12544 per-wave atomics = ~140us of pure stall in k_layernorm. Scatter over
// 64 cache lines (bucket = blockIdx & 63) + per-block pre-reduction kills it.
static constexpr int NSH       = 64;     // shadow buckets per slot
static constexpr int SH_STRIDE = 64;     // uints between buckets (256 B lines)
static constexpr int SLOTS_U32 = NSH * SH_STRIDE;   // 4096 uints = 16 KB

DEVFN float bf2f(unsigned short u){ return __uint_as_float(((unsigned)u) << 16); }
DEVFN unsigned short f2bf(float f){            // round-to-nearest-even
  unsigned u = __float_as_uint(f);
  u += 0x7fffu + ((u >> 16) & 1u);
  return (unsigned short)(u >> 16);
}
DEVFN void split_bf(float v, unsigned short& hi, unsigned short& lo){
  hi = f2bf(v);
  lo = f2bf(v - bf2f(hi));                     // v-hi is exact in fp32
}
DEVFN float slot_absmax(const unsigned* __restrict__ slots, int slot){
  unsigned m = 0u;
#pragma unroll
  for (int j = 0; j < NSH; j++){
    unsigned u = slots[j * SH_STRIDE + slot];  // uniform scalar loads, L2-hot
    m = (u > m) ? u : m;                       // bits >=0: uint order == float order
  }
  return __uint_as_float(m);
}
DEVFN float slot_scale(const unsigned* __restrict__ slots, int slot){
  return fmaxf(slot_absmax(slots, slot) / 127.0f, 1e-8f);   // exact match to ref: max/127.0
}
DEVFN void scatter_amax(unsigned* slots, int slot, unsigned bucket, float v){
  atomicMax(slots + (bucket & (NSH - 1)) * SH_STRIDE + slot, __float_as_uint(v));
}
DEVFN float quantval(float x, float s){        // integer-valued quantized result
  float q = rintf(x / s);                      // RNE, matches jnp.round
  return fminf(fmaxf(q, -128.0f), 127.0f);
}
DEVFN unsigned pack4(float a, float b, float c, float d){
  return  ((unsigned)(unsigned char)(char)(int)a)
        | ((unsigned)(unsigned char)(char)(int)b << 8)
        | ((unsigned)(unsigned char)(char)(int)c << 16)
        | ((unsigned)(unsigned char)(char)(int)d << 24);
}
DEVFN f32x4 mfma16(bf16x8 a, bf16x8 b, f32x4 c){
  return __builtin_amdgcn_mfma_f32_16x16x32_bf16(a, b, c, 0, 0, 0);
}
DEVFN i32x4 mfma16i8(i32x4 a, i32x4 b, i32x4 c){
  return __builtin_amdgcn_mfma_i32_16x16x64_i8(a, b, c, 0, 0, 0);
}
DEVFN void async_ld16(const void* g, void* lds){
  __builtin_amdgcn_global_load_lds((const __attribute__((address_space(1))) void*)g,
                                   (__attribute__((address_space(3))) void*)lds, 16, 0, 0);
}

// ---------------- init scale slots ----------------
__global__ void k_init(unsigned* slots){
  int i = blockIdx.x * blockDim.x + threadIdx.x;
  if (i < SLOTS_U32) slots[i] = 0u;
}

// ---------------- global absmax of fp32 tensor ----------------
__global__ void k_absmax(const float* __restrict__ x, int n4, unsigned* slots, int slot){
  float m = 0.f;
  const float4* x4 = (const float4*)x;
  int stride = gridDim.x * blockDim.x;
  for (int j = blockIdx.x * blockDim.x + threadIdx.x; j < n4; j += stride){
    float4 v = x4[j];
    m = fmaxf(m, fmaxf(fmaxf(fabsf(v.x), fabsf(v.y)), fmaxf(fabsf(v.z), fabsf(v.w))));
  }
  for (int off = 32; off; off >>= 1) m = fmaxf(m, __shfl_xor(m, off));
  __shared__ float wm[4];
  int lane = threadIdx.x & 63, w = threadIdx.x >> 6;
  if (lane == 0) wm[w] = m;
  __syncthreads();
  if (threadIdx.x == 0){
    float bm = fmaxf(fmaxf(wm[0], wm[1]), fmaxf(wm[2], wm[3]));
    scatter_amax(slots, slot, blockIdx.x, bm);
  }
}

// ---------------- quantize weight (K x N fp32) -> transposed int8 (N x K) ----------------
__global__ void k_quant_transpose(const float* __restrict__ w, char* __restrict__ wt,
                                  int K, int N, const unsigned* __restrict__ slots, int slot){
  __shared__ float tile[32][33];
  float s = slot_scale(slots, slot);
  int n0 = blockIdx.x * 32, k0 = blockIdx.y * 32;
  int tx = threadIdx.x & 31, ty = threadIdx.x >> 5;   // 256 threads: ty 0..7
#pragma unroll
  for (int i = 0; i < 4; i++){
    int k = k0 + ty + i * 8;
    float v = w[(size_t)k * N + n0 + tx];
    tile[ty + i * 8][tx] = quantval(v, s);
  }
  __syncthreads();
  // write: thread -> (n = tid>>3, kg = tid&7), 4 consecutive k bytes
  int n = threadIdx.x >> 3, kg = threadIdx.x & 7;
  unsigned o = pack4(tile[kg * 4 + 0][n], tile[kg * 4 + 1][n],
                     tile[kg * 4 + 2][n], tile[kg * 4 + 3][n]);
  *(unsigned*)(wt + (size_t)(n0 + n) * K + k0 + kg * 4) = o;
}

// ---------------- layernorm (rows of 768) + absmax ----------------
__global__ void k_layernorm(const float* __restrict__ x, const float* __restrict__ g,
                            const float* __restrict__ b, float* __restrict__ out,
                            unsigned* slots, int slot){
  int w = threadIdx.x >> 6, lane = threadIdx.x & 63;
  int row = blockIdx.x * 4 + w;
  const float4* xr = (const float4*)(x + (size_t)row * DMODEL);
  float4 v[3];
  float sum = 0.f;
#pragma unroll
  for (int i = 0; i < 3; i++){ v[i] = xr[i * 64 + lane]; sum += v[i].x + v[i].y + v[i].z + v[i].w; }
  for (int off = 32; off; off >>= 1) sum += __shfl_xor(sum, off);
  float mu = sum * (1.0f / 768.0f);
  float vs = 0.f;
#pragma unroll
  for (int i = 0; i < 3; i++){
    float dx = v[i].x - mu, dy = v[i].y - mu, dz = v[i].z - mu, dw = v[i].w - mu;
    vs += dx * dx + dy * dy + dz * dz + dw * dw;
  }
  for (int off = 32; off; off >>= 1) vs += __shfl_xor(vs, off);
  float inv = 1.0f / sqrtf(vs * (1.0f / 768.0f) + 1e-5f);
  const float4* g4 = (const float4*)g; const float4* b4 = (const float4*)b;
  float4* o4 = (float4*)(out + (size_t)row * DMODEL);
  float am = 0.f;
#pragma unroll
  for (int i = 0; i < 3; i++){
    float4 gg = g4[i * 64 + lane], bb = b4[i * 64 + lane], o;
    o.x = (v[i].x - mu) * inv * gg.x + bb.x;
    o.y = (v[i].y - mu) * inv * gg.y + bb.y;
    o.z = (v[i].z - mu) * inv * gg.z + bb.z;
    o.w = (v[i].w - mu) * inv * gg.w + bb.w;
    am = fmaxf(am, fmaxf(fmaxf(fabsf(o.x), fabsf(o.y)), fmaxf(fabsf(o.z), fabsf(o.w))));
    o4[i * 64 + lane] = o;
  }
  for (int off = 32; off; off >>= 1) am = fmaxf(am, __shfl_xor(am, off));
  __shared__ float am4[4];
  if (lane == 0) am4[w] = am;
  __syncthreads();
  if (threadIdx.x == 0){
    float bm = fmaxf(fmaxf(am4[0], am4[1]), fmaxf(am4[2], am4[3]));
    scatter_amax(slots, slot, blockIdx.x, bm);
  }
}

// ---------------- quantize fp32 activations -> packed int8 ----------------
__global__ void k_quant_act(const float* __restrict__ x, unsigned* __restrict__ out,
                            int n4, const unsigned* __restrict__ slots, int slot){
  float s = slot_scale(slots, slot);
  const float4* x4 = (const float4*)x;
  int stride = gridDim.x * blockDim.x;
  for (int j = blockIdx.x * blockDim.x + threadIdx.x; j < n4; j += stride){
    float4 v = x4[j];
    out[j] = pack4(quantval(v.x, s), quantval(v.y, s), quantval(v.z, s), quantval(v.w, s));
  }
}

// ---------------- quantize bf16 activations -> packed int8 ----------------
__global__ void k_quant_bf16_i8(const unsigned short* __restrict__ x, unsigned* __restrict__ out,
                                int n4, const unsigned* __restrict__ slots, int slot){
  float s = slot_scale(slots, slot);
  const ushort4* x4 = (const ushort4*)x;
  int stride = gridDim.x * blockDim.x;
  for (int j = blockIdx.x * blockDim.x + threadIdx.x; j < n4; j += stride){
    ushort4 v = x4[j];
    out[j] = pack4(quantval(bf2f(v.x), s), quantval(bf2f(v.y), s),
                   quantval(bf2f(v.z), s), quantval(bf2f(v.w), s));
  }
}

// ---------------- int8 GEMM: C[M,N] = sa*sb * (A[M,K] @ Bt[N,K]^T) + bias (+res / gelu) ---------
// mfma_i32_16x16x64_i8, BK=64, DOUBLE-BUFFERED staging with raw s_barrier + partial vmcnt:
// tile k+1's global_load_lds are in flight while tile k is consumed (no vmcnt(0) drain in loop).
// Epilogue: LDS-transpose (overlaid on tile buffers) -> coalesced float4/ushort4 global I/O.
// EPI 0: fp32 (bias) | 1: fp32 (bias+res) | 2: gelu -> absmax -> bf16
template<int EPI>
__launch_bounds__(256, 4)
__global__ void k_gemm(const char* __restrict__ A,    // M x K int8
                       const char* __restrict__ Bt,   // N x K int8
                       const float* __restrict__ bias,
                       const float* __restrict__ res,
                       float* __restrict__ Cf,
                       unsigned short* __restrict__ Cb,
                       const unsigned* __restrict__ slots, int sa_slot, int sb_slot,
                       unsigned* gmax_slots, int gmax_slot,
                       int M, int N, int K)
{
  // [0:8K)=A buf0, [8K:16K)=A buf1, [16K:24K)=B buf0, [24K:32K)=B buf1
  // epilogue stage (32*132*4 = 16896 B) overlays the same region after the loop.
  __shared__ __align__(16) char smem[32768];
  __shared__ float gm4[4];
  const int tid  = threadIdx.x;
  const int lane = tid & 63;
  const int wv   = tid >> 6;        // 0..3
  const int wx   = wv & 1, wy = wv >> 1;
  const int quad = lane >> 4;
  const int l16  = lane & 15;
  const int m0 = blockIdx.y * 128, n0 = blockIdx.x * 128;

  auto issue = [&](int k0, int buf){
#pragma unroll
    for (int i = 0; i < 2; i++){     // A tile: 512 chunks of 16B (row = c>>2, q = c&3)
      int c = tid + i * 256;
      int row = c >> 2, q = c & 3;
      async_ld16(A + (size_t)(m0 + row) * K + k0 + q * 16,
                 smem + buf * 8192 + (i * 256 + wv * 64) * 16);
    }
#pragma unroll
    for (int i = 0; i < 2; i++){     // B tile
      int c = tid + i * 256;
      int row = c >> 2, q = c & 3;
      async_ld16(Bt + (size_t)(n0 + row) * K + k0 + q * 16,
                 smem + 16384 + buf * 8192 + (i * 256 + wv * 64) * 16);
    }
  };

  i32x4 acc[4][4] = {};
  const int nk = K >> 6;
  issue(0, 0);

  for (int k = 0; k < nk; k++){
    const int cur = k & 1;
    if (k + 1 < nk){
      issue((k + 1) << 6, cur ^ 1);                       // prefetch next tile
      asm volatile("s_waitcnt vmcnt(4)" ::: "memory");    // tile-k loads landed; k+1 in flight
    } else {
      asm volatile("s_waitcnt vmcnt(0)" ::: "memory");
    }
    asm volatile("s_barrier" ::: "memory");               // tile-k visible to all waves

    const char* Ab = smem + cur * 8192;
    const char* Bb = smem + 16384 + cur * 8192;
    i32x4 af[4], bfr[4];
#pragma unroll
    for (int i = 0; i < 4; i++)
      af[i] = *(const i32x4*)(Ab + (wy * 64 + i * 16 + l16) * 64 + quad * 16);
#pragma unroll
    for (int j = 0; j < 4; j++)
      bfr[j] = *(const i32x4*)(Bb + (wx * 64 + j * 16 + l16) * 64 + quad * 16);
    asm volatile("s_waitcnt lgkmcnt(0)" ::: "memory");    // frags in regs
    asm volatile("s_barrier" ::: "memory");               // all reads of cur done -> next-iter issue may overwrite

#pragma unroll
    for (int i = 0; i < 4; i++)
#pragma unroll
      for (int j = 0; j < 4; j++)
        acc[i][j] = mfma16i8(af[i], bfr[j], acc[i][j]);
  }
  __syncthreads();   // all waves out of the K-loop before stage overlay is used

  // ---- epilogue: 4 slices of 32 rows; LDS transpose -> coalesced wide loads/stores ----
  float (*stage)[132] = (float (*)[132])smem;   // 16896 B, overlays dead tile buffers
  const float sc = slot_scale(slots, sa_slot) * slot_scale(slots, sb_slot);
  const int col4 = (tid & 31) * 4;           // 0..124
  const int gc   = n0 + col4;
  const float4 bb = *(const float4*)&bias[gc];   // column-only: hoisted out of slice loop
  float gmax = 0.f;
#pragma unroll
  for (int i = 0; i < 4; i++){
    // write: LDS row = wy*16 + quad*4 + r  <=>  global m = m0 + wy*64 + i*16 + quad*4 + r
#pragma unroll
    for (int j = 0; j < 4; j++)
#pragma unroll
      for (int r = 0; r < 4; r++)
        stage[wy * 16 + quad * 4 + r][wx * 64 + j * 16 + l16] = (float)acc[i][j][r];
    __syncthreads();
    // read: thread t -> rows rr*8 + (t>>5) (rr=0..3), cols col4..col4+3 (coalesced)
#pragma unroll
    for (int rr = 0; rr < 4; rr++){
      const int rl = rr * 8 + (tid >> 5);                       // 0..31
      const int gm = m0 + ((rl >> 4) * 64) + i * 16 + (rl & 15);
      float4 v = *(const float4*)&stage[rl][col4];
      v.x = v.x * sc + bb.x; v.y = v.y * sc + bb.y;
      v.z = v.z * sc + bb.z; v.w = v.w * sc + bb.w;
      if constexpr (EPI == 1){
        float4 rv = *(const float4*)&res[(size_t)gm * N + gc];
        v.x += rv.x; v.y += rv.y; v.z += rv.z; v.w += rv.w;
        *(float4*)&Cf[(size_t)gm * N + gc] = v;
      } else if constexpr (EPI == 2){
        float g0 = 0.5f * v.x * (1.0f + erff(v.x * 0.70710678118654752f));
        float g1 = 0.5f * v.y * (1.0f + erff(v.y * 0.70710678118654752f));
        float g2 = 0.5f * v.z * (1.0f + erff(v.z * 0.70710678118654752f));
        float g3 = 0.5f * v.w * (1.0f + erff(v.w * 0.70710678118654752f));
        gmax = fmaxf(gmax, fmaxf(fmaxf(fabsf(g0), fabsf(g1)), fmaxf(fabsf(g2), fabsf(g3))));
        ushort4 o = {f2bf(g0), f2bf(g1), f2bf(g2), f2bf(g3)};
        *(ushort4*)&Cb[(size_t)gm * N + gc] = o;
      } else {
        *(float4*)&Cf[(size_t)gm * N + gc] = v;
      }
    }
    __syncthreads();
  }
  if constexpr (EPI == 2){
    for (int off = 32; off; off >>= 1) gmax = fmaxf(gmax, __shfl_xor(gmax, off));
    if (lane == 0) gm4[wv] = gmax;
    __syncthreads();
    if (tid == 0){
      float bm = fmaxf(fmaxf(gm4[0], gm4[1]), fmaxf(gm4[2], gm4[3]));
      scatter_amax(gmax_slots, gmax_slot, blockIdx.x + blockIdx.y * gridDim.x, bm);
    }
  }
}

// ---------------- attention: one block per (b,h), 8 waves, barrier-free main loop --------------
__launch_bounds__(512, 2)
__global__ void k_attention(const float* __restrict__ qkv, float* __restrict__ ctx,
                            unsigned* slots){
  __shared__ __align__(16) unsigned short Khi[208 * 72], Klo[208 * 72];   // 59,904 B
  __shared__ __align__(16) unsigned short Vhi[64 * 232], Vlo[64 * 232];   // 59,392 B
  __shared__ __align__(16) unsigned short Ps[8][2][16 * 40];              // 20,480 B (per-wave hi/lo)
  __shared__ float gm8[8];

  const int bh = blockIdx.x;
  const int b = bh / NHEAD, h = bh % NHEAD;
  const float* base = qkv + (size_t)b * SEQ * NQKV;
  const int tid = threadIdx.x, lane = tid & 63, wv = tid >> 6;
  const int quad = lane >> 4, l16 = lane & 15;

  // ---- stage K (208 rows x 64, zero-padded rows) : coalesced float4 ----
  for (int idx = tid; idx < 208 * 16; idx += 512){
    int r = idx >> 4, c4 = (idx & 15) * 4;
    float4 v = {0.f, 0.f, 0.f, 0.f};
    if (r < SEQ) v = *(const float4*)(base + (size_t)r * NQKV + DMODEL + h * 64 + c4);
    unsigned short h0,l0,h1,l1,h2,l2,h3,l3;
    split_bf(v.x, h0, l0); split_bf(v.y, h1, l1); split_bf(v.z, h2, l2); split_bf(v.w, h3, l3);
    ushort4 hs = {h0, h1, h2, h3}, ls = {l0, l1, l2, l3};
    *(ushort4*)(Khi + r * 72 + c4) = hs;
    *(ushort4*)(Klo + r * 72 + c4) = ls;
  }
  // ---- stage V^T (64 rows x 232, cols >=196 zeroed) ----
  for (int idx = tid; idx < SEQ * 16; idx += 512){
    int s = idx >> 4, dg = (idx & 15) * 4;
    float4 v = *(const float4*)(base + (size_t)s * NQKV + 2 * DMODEL + h * 64 + dg);
    unsigned short hi, lo;
    split_bf(v.x, hi, lo); Vhi[(dg + 0) * 232 + s] = hi; Vlo[(dg + 0) * 232 + s] = lo;
    split_bf(v.y, hi, lo); Vhi[(dg + 1) * 232 + s] = hi; Vlo[(dg + 1) * 232 + s] = lo;
    split_bf(v.z, hi, lo); Vhi[(dg + 2) * 232 + s] = hi; Vlo[(dg + 2) * 232 + s] = lo;
    split_bf(v.w, hi, lo); Vhi[(dg + 3) * 232 + s] = hi; Vlo[(dg + 3) * 232 + s] = lo;
  }
  for (int idx = tid; idx < 64 * 36; idx += 512){
    int d = idx / 36, c = idx - d * 36;
    Vhi[d * 232 + SEQ + c] = 0; Vlo[d * 232 + SEQ + c] = 0;
  }
  __syncthreads();    // the ONLY full-block barrier in the main body

  unsigned short* PsH = &Ps[wv][0][0];
  unsigned short* PsL = &Ps[wv][1][0];

  float gmax = 0.f;
  for (int qt = wv; qt < 13; qt += 8){
    const int q0 = qt * 16;
    const int sq = q0 + l16;
    const bool valid = sq < SEQ;

    // Q fragments straight from global (A-layout: m=l16, k=quad*8+j), split hi/lo
    bf16x8 aqh[2], aql[2];
    const float* qrow = base + (size_t)(valid ? sq : 0) * NQKV + h * 64;
#pragma unroll
    for (int ks = 0; ks < 2; ks++){
      float4 v0 = {0,0,0,0}, v1 = {0,0,0,0};
      if (valid){
        v0 = *(const float4*)(qrow + ks * 32 + quad * 8);
        v1 = *(const float4*)(qrow + ks * 32 + quad * 8 + 4);
      }
      float vv[8] = {v0.x, v0.y, v0.z, v0.w, v1.x, v1.y, v1.z, v1.w};
#pragma unroll
      for (int j = 0; j < 8; j++){
        unsigned short hi, lo; split_bf(vv[j], hi, lo);
        aqh[ks][j] = (short)hi; aql[ks][j] = (short)lo;
      }
    }

    // ---- S = Q K^T / 8 : 13 independent MFMA chains ----
    f32x4 sacc[13];
#pragma unroll
    for (int t = 0; t < 13; t++){
      f32x4 a = {0.f, 0.f, 0.f, 0.f};
#pragma unroll
      for (int ks = 0; ks < 2; ks++){
        bf16x8 bkh = *(const bf16x8*)(Khi + (t * 16 + l16) * 72 + ks * 32 + quad * 8);
        bf16x8 bkl = *(const bf16x8*)(Klo + (t * 16 + l16) * 72 + ks * 32 + quad * 8);
        a = mfma16(aqh[ks], bkh, a);
        a = mfma16(aqh[ks], bkl, a);
        a = mfma16(aql[ks], bkh, a);
      }
      sacc[t] = a;
    }

    // ---- softmax in registers: lane holds rows q=quad*4+r, cols s=t*16+l16 ----
    float mx[4] = {-1e30f, -1e30f, -1e30f, -1e30f};
#pragma unroll
    for (int t = 0; t < 13; t++){
      bool dead = (t == 12) && (l16 >= 4);   // col >= 196
#pragma unroll
      for (int r = 0; r < 4; r++){
        float v = dead ? -1e30f : sacc[t][r] * 0.125f;
        sacc[t][r] = v;
        mx[r] = fmaxf(mx[r], v);
      }
    }
#pragma unroll
    for (int off = 1; off < 16; off <<= 1)
#pragma unroll
      for (int r = 0; r < 4; r++) mx[r] = fmaxf(mx[r], __shfl_xor(mx[r], off));
    float sum[4] = {0.f, 0.f, 0.f, 0.f};
#pragma unroll
    for (int t = 0; t < 13; t++)
#pragma unroll
      for (int r = 0; r < 4; r++){
        float e = __expf(sacc[t][r] - mx[r]);
        sacc[t][r] = e; sum[r] += e;
      }
#pragma unroll
    for (int off = 1; off < 16; off <<= 1)
#pragma unroll
      for (int r = 0; r < 4; r++) sum[r] += __shfl_xor(sum[r], off);
    float inv[4];
#pragma unroll
    for (int r = 0; r < 4; r++) inv[r] = 1.0f / sum[r];

    // ---- O = P V : per-ks transpose C->A layout through per-wave scratch, no barrier ----
    f32x4 oacc[4] = {};
#pragma unroll
    for (int ks = 0; ks < 7; ks++){
      const int t0 = 2 * ks, t1 = 2 * ks + 1;
#pragma unroll
      for (int r = 0; r < 4; r++){
        int row = quad * 4 + r;
        unsigned short hi, lo;
        split_bf(sacc[t0][r] * inv[r], hi, lo);
        PsH[row * 40 + l16] = hi; PsL[row * 40 + l16] = lo;
        if (t1 < 13){
          split_bf(sacc[t1][r] * inv[r], hi, lo);
          PsH[row * 40 + 16 + l16] = hi; PsL[row * 40 + 16 + l16] = lo;
        } else {
          PsH[row * 40 + 16 + l16] = 0; PsL[row * 40 + 16 + l16] = 0;
        }
      }
      __builtin_amdgcn_wave_barrier();   // keep compiler from reordering the RAW through LDS
      bf16x8 aph = *(const bf16x8*)(PsH + l16 * 40 + quad * 8);
      bf16x8 apl = *(const bf16x8*)(PsL + l16 * 40 + quad * 8);
#pragma unroll
      for (int n = 0; n < 4; n++){
        bf16x8 bvh = *(const bf16x8*)(Vhi + (n * 16 + l16) * 232 + ks * 32 + quad * 8);
        bf16x8 bvl = *(const bf16x8*)(Vlo + (n * 16 + l16) * 232 + ks * 32 + quad * 8);
        oacc[n] = mfma16(aph, bvh, oacc[n]);
        oacc[n] = mfma16(aph, bvl, oacc[n]);
        oacc[n] = mfma16(apl, bvh, oacc[n]);
      }
      __builtin_amdgcn_wave_barrier();   // reads of this slice complete before next-iter writes
    }

    // ---- store ctx (C-layout: row=quad*4+r, col=n*16+l16) + absmax ----
#pragma unroll
    for (int r = 0; r < 4; r++){
      int srow = q0 + quad * 4 + r;
      if (srow < SEQ){
#pragma unroll
        for (int n = 0; n < 4; n++){
          float v = oacc[n][r];
          ctx[((size_t)(b * SEQ + srow)) * DMODEL + h * 64 + n * 16 + l16] = v;
          gmax = fmaxf(gmax, fabsf(v));
        }
      }
    }
  }
  for (int off = 32; off; off >>= 1) gmax = fmaxf(gmax, __shfl_xor(gmax, off));
  if (lane == 0) gm8[wv] = gmax;
  __syncthreads();
  if (tid == 0){
    float bm = 0.f;
#pragma unroll
    for (int i = 0; i < 8; i++) bm = fmaxf(bm, gm8[i]);
    scatter_amax(slots, SL_CTX, blockIdx.x, bm);
  }
}

// ---------------- launch ----------------
extern "C" void kernel_launch(void* const* d_in, const int* in_sizes, int n_in,
                              void* d_out, int out_size, void* d_ws, size_t ws_size,
                              hipStream_t stream)
{
  const float* x     = (const float*)d_in[0];
  const float* ln1_g = (const float*)d_in[1];
  const float* ln1_b = (const float*)d_in[2];
  const float* ln2_g = (const float*)d_in[3];
  const float* ln2_b = (const float*)d_in[4];
  const float* w_qkv = (const float*)d_in[5];
  const float* b_qkv = (const float*)d_in[6];
  const float* w_o   = (const float*)d_in[7];
  const float* b_o   = (const float*)d_in[8];
  const float* w1    = (const float*)d_in[9];
  const float* b1    = (const float*)d_in[10];
  const float* w2    = (const float*)d_in[11];
  const float* b2    = (const float*)d_in[12];

  char* ws = (char*)d_ws;
  size_t off = 0;
  unsigned* slots = (unsigned*)ws;                 off += SLOTS_U32 * 4;   // 16 KB scattered slots
  char* wqkvT = (char*)(ws + off); off += (size_t)NQKV  * DMODEL;
  char* woT   = (char*)(ws + off); off += (size_t)DMODEL* DMODEL;
  char* w1T   = (char*)(ws + off); off += (size_t)MMLP  * DMODEL;
  char* w2T   = (char*)(ws + off); off += (size_t)DMODEL* MMLP;
  off = (off + 255) & ~(size_t)255;
  float* t1    = (float*)(ws + off);               off += (size_t)NTOK * DMODEL * 4;
  char*  t1q   = (char*)(ws + off);                off += (size_t)NTOK * DMODEL;
  off = (off + 255) & ~(size_t)255;
  float* qkv   = (float*)(ws + off);               off += (size_t)NTOK * NQKV * 4;
  float* xmid  = (float*)(ws + off);               off += (size_t)NTOK * DMODEL * 4;
  // FC1 bf16 output (77.07 MB) + its int8 quant (38.54 MB) exactly fill the qkv region (115.6 MB)
  unsigned short* h1 = (unsigned short*)qkv;
  char* h1q = (char*)qkv + (size_t)NTOK * MMLP * 2;
  float* outp = (float*)d_out;

  k_init<<<(SLOTS_U32 + 255) / 256, 256, 0, stream>>>(slots);

  k_absmax<<<256, 256, 0, stream>>>(w_qkv, DMODEL * NQKV / 4, slots, SL_WQKV);
  k_absmax<<<128, 256, 0, stream>>>(w_o,   DMODEL * DMODEL / 4, slots, SL_WO);
  k_absmax<<<256, 256, 0, stream>>>(w1,    DMODEL * MMLP / 4, slots, SL_W1);
  k_absmax<<<256, 256, 0, stream>>>(w2,    MMLP * DMODEL / 4, slots, SL_W2);

  k_quant_transpose<<<dim3(NQKV / 32, DMODEL / 32), 256, 0, stream>>>(w_qkv, wqkvT, DMODEL, NQKV, slots, SL_WQKV);
  k_quant_transpose<<<dim3(DMODEL / 32, DMODEL / 32), 256, 0, stream>>>(w_o, woT, DMODEL, DMODEL, slots, SL_WO);
  k_quant_transpose<<<dim3(MMLP / 32, DMODEL / 32), 256, 0, stream>>>(w1, w1T, DMODEL, MMLP, slots, SL_W1);
  k_quant_transpose<<<dim3(DMODEL / 32, MMLP / 32), 256, 0, stream>>>(w2, w2T, MMLP, DMODEL, slots, SL_W2);

  // LN1 -> quant -> QKV
  k_layernorm<<<NTOK / 4, 256, 0, stream>>>(x, ln1_g, ln1_b, t1, slots, SL_LN1);
  {
    int n4 = NTOK * DMODEL / 4;
    k_quant_act<<<(n4 + 255) / 256, 256, 0, stream>>>(t1, (unsigned*)t1q, n4, slots, SL_LN1);
  }
  k_gemm<0><<<dim3(NQKV / 128, NTOK / 128), 256, 0, stream>>>(
      t1q, wqkvT, b_qkv, nullptr, qkv, nullptr, slots, SL_LN1, SL_WQKV, nullptr, 0,
      NTOK, NQKV, DMODEL);

  // attention -> ctx (t1) + absmax
  k_attention<<<NBATCH * NHEAD, 512, 0, stream>>>(qkv, t1, slots);
  {
    int n4 = NTOK * DMODEL / 4;
    k_quant_act<<<(n4 + 255) / 256, 256, 0, stream>>>(t1, (unsigned*)t1q, n4, slots, SL_CTX);
  }
  // O-proj + residual -> xmid
  k_gemm<1><<<dim3(DMODEL / 128, NTOK / 128), 256, 0, stream>>>(
      t1q, woT, b_o, x, xmid, nullptr, slots, SL_CTX, SL_WO, nullptr, 0,
      NTOK, DMODEL, DMODEL);

  // LN2 -> quant -> FC1(+gelu->bf16) -> quant -> FC2 + residual -> out
  k_layernorm<<<NTOK / 4, 256, 0, stream>>>(xmid, ln2_g, ln2_b, t1, slots, SL_LN2);
  {
    int n4 = NTOK * DMODEL / 4;
    k_quant_act<<<(n4 + 255) / 256, 256, 0, stream>>>(t1, (unsigned*)t1q, n4, slots, SL_LN2);
  }
  k_gemm<2><<<dim3(MMLP / 128, NTOK / 128), 256, 0, stream>>>(
      t1q, w1T, b1, nullptr, nullptr, h1, slots, SL_LN2, SL_W1, slots, SL_GELU,
      NTOK, MMLP, DMODEL);
  {
    int n4 = NTOK * MMLP / 4;
    k_quant_bf16_i8<<<(n4 + 255) / 256, 256, 0, stream>>>(h1, (unsigned*)h1q, n4, slots, SL_GELU);
  }
  k_gemm<1><<<dim3(DMODEL / 128, NTOK / 128), 256, 0, stream>>>(
      h1q, w2T, b2, xmid, outp, nullptr, slots, SL_GELU, SL_W2, nullptr, 0,
      NTOK, DMODEL, MMLP);
}

// Round 2
// 515.103 us; speedup vs baseline: 1.6860x; 1.0418x over previous
//
#include <hip/hip_runtime.h>
#include <cstdint>
#include <cstddef>

#define DEVFN __device__ __forceinline__

typedef short bf16x8 __attribute__((ext_vector_type(8)));
typedef float f32x4  __attribute__((ext_vector_type(4)));
typedef int   i32x4  __attribute__((ext_vector_type(4)));

// problem constants
static constexpr int NTOK  = 64 * 196;   // 12544  (= 98 * 128)
static constexpr int DMODEL= 768;
static constexpr int NHEAD = 12;
static constexpr int NQKV  = 2304;       // 3*768 (= 18 * 128)
static constexpr int MMLP  = 3072;       // 4*768 (= 24 * 128)
static constexpr int SEQ   = 196;
static constexpr int NBATCH= 64;

// scale slots (absmax bits, atomicMax on uint reinterpretation of fp32)
enum { SL_LN1=0, SL_WQKV=1, SL_CTX=2, SL_WO=3, SL_LN2=4, SL_W1=5, SL_GELU=6, SL_W2=7 };

// ---- scattered absmax slots: 64 shadow copies per logical slot, 256B apart ----
static constexpr int NSH       = 64;     // shadow buckets per slot
static constexpr int SH_STRIDE = 64;     // uints between buckets (256 B lines)
static constexpr int SLOTS_U32 = NSH * SH_STRIDE;   // 4096 uints = 16 KB

DEVFN float bf2f(unsigned short u){ return __uint_as_float(((unsigned)u) << 16); }
DEVFN unsigned short f2bf(float f){            // round-to-nearest-even
  unsigned u = __float_as_uint(f);
  u += 0x7fffu + ((u >> 16) & 1u);
  return (unsigned short)(u >> 16);
}
DEVFN void split_bf(float v, unsigned short& hi, unsigned short& lo){
  hi = f2bf(v);
  lo = f2bf(v - bf2f(hi));                     // v-hi is exact in fp32
}
DEVFN float slot_absmax(const unsigned* __restrict__ slots, int slot){
  unsigned m = 0u;
#pragma unroll
  for (int j = 0; j < NSH; j++){
    unsigned u = slots[j * SH_STRIDE + slot];  // uniform scalar loads, L2-hot
    m = (u > m) ? u : m;                       // bits >=0: uint order == float order
  }
  return __uint_as_float(m);
}
DEVFN float slot_scale(const unsigned* __restrict__ slots, int slot){
  return fmaxf(slot_absmax(slots, slot) / 127.0f, 1e-8f);   // exact match to ref: max/127.0
}
DEVFN void scatter_amax(unsigned* slots, int slot, unsigned bucket, float v){
  atomicMax(slots + (bucket & (NSH - 1)) * SH_STRIDE + slot, __float_as_uint(v));
}
DEVFN float quantval(float x, float s){        // integer-valued quantized result
  float q = rintf(x / s);                      // RNE, matches jnp.round
  return fminf(fmaxf(q, -128.0f), 127.0f);
}
DEVFN unsigned pack4(float a, float b, float c, float d){
  return  ((unsigned)(unsigned char)(char)(int)a)
        | ((unsigned)(unsigned char)(char)(int)b << 8)
        | ((unsigned)(unsigned char)(char)(int)c << 16)
        | ((unsigned)(unsigned char)(char)(int)d << 24);
}
// exact-GELU with branch-free A&S 7.1.26 erf (max abs err 1.5e-7, invisible
// under the immediate bf16 rounding of the result).  ~15 VALU ops vs OCML
// erff's ~60-80 with divergent branches.
DEVFN float gelu_fast(float v){
  float s  = v * 0.70710678118654752f;
  float ax = fabsf(s);
  float t  = __builtin_amdgcn_rcpf(fmaf(0.3275911f, ax, 1.0f));
  float p  = t * fmaf(t, fmaf(t, fmaf(t, fmaf(t, 1.061405429f, -1.453152027f),
                                      1.421413741f), -0.284496736f), 0.254829592f);
  float er = fmaf(-p, __expf(-ax * ax), 1.0f);           // erf(|s|) in [0,1)
  // apply sign of s: gelu = 0.5*v*(1 + sign(s)*er)
  unsigned sgn = __float_as_uint(s) & 0x80000000u;
  er = __uint_as_float(__float_as_uint(er) | sgn);
  return 0.5f * v * (1.0f + er);
}
DEVFN f32x4 mfma16(bf16x8 a, bf16x8 b, f32x4 c){
  return __builtin_amdgcn_mfma_f32_16x16x32_bf16(a, b, c, 0, 0, 0);
}
DEVFN i32x4 mfma16i8(i32x4 a, i32x4 b, i32x4 c){
  return __builtin_amdgcn_mfma_i32_16x16x64_i8(a, b, c, 0, 0, 0);
}
DEVFN void async_ld16(const void* g, void* lds){
  __builtin_amdgcn_global_load_lds((const __attribute__((address_space(1))) void*)g,
                                   (__attribute__((address_space(3))) void*)lds, 16, 0, 0);
}

// ---------------- init scale slots ----------------
__global__ void k_init(unsigned* slots){
  int i = blockIdx.x * blockDim.x + threadIdx.x;
  if (i < SLOTS_U32) slots[i] = 0u;
}

// ---------------- global absmax of fp32 tensor ----------------
__global__ void k_absmax(const float* __restrict__ x, int n4, unsigned* slots, int slot){
  float m = 0.f;
  const float4* x4 = (const float4*)x;
  int stride = gridDim.x * blockDim.x;
  for (int j = blockIdx.x * blockDim.x + threadIdx.x; j < n4; j += stride){
    float4 v = x4[j];
    m = fmaxf(m, fmaxf(fmaxf(fabsf(v.x), fabsf(v.y)), fmaxf(fabsf(v.z), fabsf(v.w))));
  }
  for (int off = 32; off; off >>= 1) m = fmaxf(m, __shfl_xor(m, off));
  __shared__ float wm[4];
  int lane = threadIdx.x & 63, w = threadIdx.x >> 6;
  if (lane == 0) wm[w] = m;
  __syncthreads();
  if (threadIdx.x == 0){
    float bm = fmaxf(fmaxf(wm[0], wm[1]), fmaxf(wm[2], wm[3]));
    scatter_amax(slots, slot, blockIdx.x, bm);
  }
}

// ---------------- quantize weight (K x N fp32) -> transposed int8 (N x K) ----------------
__global__ void k_quant_transpose(const float* __restrict__ w, char* __restrict__ wt,
                                  int K, int N, const unsigned* __restrict__ slots, int slot){
  __shared__ float tile[32][33];
  float s = slot_scale(slots, slot);
  int n0 = blockIdx.x * 32, k0 = blockIdx.y * 32;
  int tx = threadIdx.x & 31, ty = threadIdx.x >> 5;   // 256 threads: ty 0..7
#pragma unroll
  for (int i = 0; i < 4; i++){
    int k = k0 + ty + i * 8;
    float v = w[(size_t)k * N + n0 + tx];
    tile[ty + i * 8][tx] = quantval(v, s);
  }
  __syncthreads();
  // write: thread -> (n = tid>>3, kg = tid&7), 4 consecutive k bytes
  int n = threadIdx.x >> 3, kg = threadIdx.x & 7;
  unsigned o = pack4(tile[kg * 4 + 0][n], tile[kg * 4 + 1][n],
                     tile[kg * 4 + 2][n], tile[kg * 4 + 3][n]);
  *(unsigned*)(wt + (size_t)(n0 + n) * K + k0 + kg * 4) = o;
}

// ---------------- layernorm (rows of 768) + absmax ----------------
__global__ void k_layernorm(const float* __restrict__ x, const float* __restrict__ g,
                            const float* __restrict__ b, float* __restrict__ out,
                            unsigned* slots, int slot){
  int w = threadIdx.x >> 6, lane = threadIdx.x & 63;
  int row = blockIdx.x * 4 + w;
  const float4* xr = (const float4*)(x + (size_t)row * DMODEL);
  float4 v[3];
  float sum = 0.f;
#pragma unroll
  for (int i = 0; i < 3; i++){ v[i] = xr[i * 64 + lane]; sum += v[i].x + v[i].y + v[i].z + v[i].w; }
  for (int off = 32; off; off >>= 1) sum += __shfl_xor(sum, off);
  float mu = sum * (1.0f / 768.0f);
  float vs = 0.f;
#pragma unroll
  for (int i = 0; i < 3; i++){
    float dx = v[i].x - mu, dy = v[i].y - mu, dz = v[i].z - mu, dw = v[i].w - mu;
    vs += dx * dx + dy * dy + dz * dz + dw * dw;
  }
  for (int off = 32; off; off >>= 1) vs += __shfl_xor(vs, off);
  float inv = 1.0f / sqrtf(vs * (1.0f / 768.0f) + 1e-5f);
  const float4* g4 = (const float4*)g; const float4* b4 = (const float4*)b;
  float4* o4 = (float4*)(out + (size_t)row * DMODEL);
  float am = 0.f;
#pragma unroll
  for (int i = 0; i < 3; i++){
    float4 gg = g4[i * 64 + lane], bb = b4[i * 64 + lane], o;
    o.x = (v[i].x - mu) * inv * gg.x + bb.x;
    o.y = (v[i].y - mu) * inv * gg.y + bb.y;
    o.z = (v[i].z - mu) * inv * gg.z + bb.z;
    o.w = (v[i].w - mu) * inv * gg.w + bb.w;
    am = fmaxf(am, fmaxf(fmaxf(fabsf(o.x), fabsf(o.y)), fmaxf(fabsf(o.z), fabsf(o.w))));
    o4[i * 64 + lane] = o;
  }
  for (int off = 32; off; off >>= 1) am = fmaxf(am, __shfl_xor(am, off));
  __shared__ float am4[4];
  if (lane == 0) am4[w] = am;
  __syncthreads();
  if (threadIdx.x == 0){
    float bm = fmaxf(fmaxf(am4[0], am4[1]), fmaxf(am4[2], am4[3]));
    scatter_amax(slots, slot, blockIdx.x, bm);
  }
}

// ---------------- quantize fp32 activations -> packed int8 ----------------
__global__ void k_quant_act(const float* __restrict__ x, unsigned* __restrict__ out,
                            int n4, const unsigned* __restrict__ slots, int slot){
  float s = slot_scale(slots, slot);
  const float4* x4 = (const float4*)x;
  int stride = gridDim.x * blockDim.x;
  for (int j = blockIdx.x * blockDim.x + threadIdx.x; j < n4; j += stride){
    float4 v = x4[j];
    out[j] = pack4(quantval(v.x, s), quantval(v.y, s), quantval(v.z, s), quantval(v.w, s));
  }
}

// ---------------- quantize bf16 activations -> packed int8 ----------------
__global__ void k_quant_bf16_i8(const unsigned short* __restrict__ x, unsigned* __restrict__ out,
                                int n4, const unsigned* __restrict__ slots, int slot){
  float s = slot_scale(slots, slot);
  const ushort4* x4 = (const ushort4*)x;
  int stride = gridDim.x * blockDim.x;
  for (int j = blockIdx.x * blockDim.x + threadIdx.x; j < n4; j += stride){
    ushort4 v = x4[j];
    out[j] = pack4(quantval(bf2f(v.x), s), quantval(bf2f(v.y), s),
                   quantval(bf2f(v.z), s), quantval(bf2f(v.w), s));
  }
}

// ---------------- int8 GEMM: C[M,N] = sa*sb * (A[M,K] @ Bt[N,K]^T) + bias (+res / gelu) ---------
// mfma_i32_16x16x64_i8, BK=64, DOUBLE-BUFFERED staging with raw s_barrier + partial vmcnt.
// LDS tiles are chunk-rotated (rot(row)=(row+(row>>2))&3, applied on the per-lane GLOBAL
// source address since global_load_lds dest is linear) so the fragment ds_read_b128s are
// bank-conflict-free (was 8-way / 3.6M conflict cycles per dispatch).
// Epilogue: LDS-transpose (overlaid on tile buffers) -> coalesced float4/ushort4 global I/O.
// EPI 0: fp32 (bias) | 1: fp32 (bias+res) | 2: gelu -> absmax -> bf16
template<int EPI>
__launch_bounds__(256, 4)
__global__ void k_gemm(const char* __restrict__ A,    // M x K int8
                       const char* __restrict__ Bt,   // N x K int8
                       const float* __restrict__ bias,
                       const float* __restrict__ res,
                       float* __restrict__ Cf,
                       unsigned short* __restrict__ Cb,
                       const unsigned* __restrict__ slots, int sa_slot, int sb_slot,
                       unsigned* gmax_slots, int gmax_slot,
                       int M, int N, int K)
{
  // [0:8K)=A buf0, [8K:16K)=A buf1, [16K:24K)=B buf0, [24K:32K)=B buf1
  // epilogue stage (32*132*4 = 16896 B) overlays the same region after the loop.
  __shared__ __align__(16) char smem[32768];
  __shared__ float gm4[4];
  const int tid  = threadIdx.x;
  const int lane = tid & 63;
  const int wv   = tid >> 6;        // 0..3
  const int wx   = wv & 1, wy = wv >> 1;
  const int quad = lane >> 4;
  const int l16  = lane & 15;
  const int m0 = blockIdx.y * 128, n0 = blockIdx.x * 128;

  auto issue = [&](int k0, int buf){
#pragma unroll
    for (int i = 0; i < 2; i++){     // A tile: 512 chunks of 16B (row = c>>2, q = c&3)
      int c = tid + i * 256;
      int row = c >> 2, q = c & 3;
      int qs = (q - ((row + (row >> 2)) & 3)) & 3;   // inverse chunk rotation
      async_ld16(A + (size_t)(m0 + row) * K + k0 + qs * 16,
                 smem + buf * 8192 + (i * 256 + wv * 64) * 16);
    }
#pragma unroll
    for (int i = 0; i < 2; i++){     // B tile
      int c = tid + i * 256;
      int row = c >> 2, q = c & 3;
      int qs = (q - ((row + (row >> 2)) & 3)) & 3;
      async_ld16(Bt + (size_t)(n0 + row) * K + k0 + qs * 16,
                 smem + 16384 + buf * 8192 + (i * 256 + wv * 64) * 16);
    }
  };

  i32x4 acc[4][4] = {};
  const int nk = K >> 6;
  issue(0, 0);

  // chunk rotation for the fragment reads: rot(row) depends only on l16
  // (row = {wy,wx}*64 + i*16 + l16; the *64 and *16 parts are ≡0 mod 4 in both fields)
  const int ch = (((quad + (l16 & 3) + (l16 >> 2)) & 3)) * 16;

  for (int k = 0; k < nk; k++){
    const int cur = k & 1;
    if (k + 1 < nk){
      issue((k + 1) << 6, cur ^ 1);                       // prefetch next tile
      asm volatile("s_waitcnt vmcnt(4)" ::: "memory");    // tile-k loads landed; k+1 in flight
    } else {
      asm volatile("s_waitcnt vmcnt(0)" ::: "memory");
    }
    asm volatile("s_barrier" ::: "memory");               // tile-k visible to all waves

    const char* Ab = smem + cur * 8192;
    const char* Bb = smem + 16384 + cur * 8192;
    i32x4 af[4], bfr[4];
#pragma unroll
    for (int i = 0; i < 4; i++)
      af[i] = *(const i32x4*)(Ab + (wy * 64 + i * 16 + l16) * 64 + ch);
#pragma unroll
    for (int j = 0; j < 4; j++)
      bfr[j] = *(const i32x4*)(Bb + (wx * 64 + j * 16 + l16) * 64 + ch);
    asm volatile("s_waitcnt lgkmcnt(0)" ::: "memory");    // frags in regs
    asm volatile("s_barrier" ::: "memory");               // all reads of cur done -> next-iter issue may overwrite

#pragma unroll
    for (int i = 0; i < 4; i++)
#pragma unroll
      for (int j = 0; j < 4; j++)
        acc[i][j] = mfma16i8(af[i], bfr[j], acc[i][j]);
  }
  __syncthreads();   // all waves out of the K-loop before stage overlay is used

  // ---- epilogue: 4 slices of 32 rows; LDS transpose -> coalesced wide loads/stores ----
  float (*stage)[132] = (float (*)[132])smem;   // 16896 B, overlays dead tile buffers
  const float sc = slot_scale(slots, sa_slot) * slot_scale(slots, sb_slot);
  const int col4 = (tid & 31) * 4;           // 0..124
  const int gc   = n0 + col4;
  const float4 bb = *(const float4*)&bias[gc];   // column-only: hoisted out of slice loop
  float gmax = 0.f;
#pragma unroll
  for (int i = 0; i < 4; i++){
    // write: LDS row = wy*16 + quad*4 + r  <=>  global m = m0 + wy*64 + i*16 + quad*4 + r
#pragma unroll
    for (int j = 0; j < 4; j++)
#pragma unroll
      for (int r = 0; r < 4; r++)
        stage[wy * 16 + quad * 4 + r][wx * 64 + j * 16 + l16] = (float)acc[i][j][r];
    __syncthreads();
    // read: thread t -> rows rr*8 + (t>>5) (rr=0..3), cols col4..col4+3 (coalesced)
#pragma unroll
    for (int rr = 0; rr < 4; rr++){
      const int rl = rr * 8 + (tid >> 5);                       // 0..31
      const int gm = m0 + ((rl >> 4) * 64) + i * 16 + (rl & 15);
      float4 v = *(const float4*)&stage[rl][col4];
      v.x = v.x * sc + bb.x; v.y = v.y * sc + bb.y;
      v.z = v.z * sc + bb.z; v.w = v.w * sc + bb.w;
      if constexpr (EPI == 1){
        float4 rv = *(const float4*)&res[(size_t)gm * N + gc];
        v.x += rv.x; v.y += rv.y; v.z += rv.z; v.w += rv.w;
        *(float4*)&Cf[(size_t)gm * N + gc] = v;
      } else if constexpr (EPI == 2){
        float g0 = gelu_fast(v.x);
        float g1 = gelu_fast(v.y);
        float g2 = gelu_fast(v.z);
        float g3 = gelu_fast(v.w);
        gmax = fmaxf(gmax, fmaxf(fmaxf(fabsf(g0), fabsf(g1)), fmaxf(fabsf(g2), fabsf(g3))));
        ushort4 o = {f2bf(g0), f2bf(g1), f2bf(g2), f2bf(g3)};
        *(ushort4*)&Cb[(size_t)gm * N + gc] = o;
      } else {
        *(float4*)&Cf[(size_t)gm * N + gc] = v;
      }
    }
    __syncthreads();
  }
  if constexpr (EPI == 2){
    for (int off = 32; off; off >>= 1) gmax = fmaxf(gmax, __shfl_xor(gmax, off));
    if (lane == 0) gm4[wv] = gmax;
    __syncthreads();
    if (tid == 0){
      float bm = fmaxf(fmaxf(gm4[0], gm4[1]), fmaxf(gm4[2], gm4[3]));
      scatter_amax(gmax_slots, gmax_slot, blockIdx.x + blockIdx.y * gridDim.x, bm);
    }
  }
}

// ---------------- attention: one block per (b,h), 8 waves, barrier-free main loop --------------
__launch_bounds__(512, 2)
__global__ void k_attention(const float* __restrict__ qkv, float* __restrict__ ctx,
                            unsigned* slots){
  __shared__ __align__(16) unsigned short Khi[208 * 72], Klo[208 * 72];   // 59,904 B
  __shared__ __align__(16) unsigned short Vhi[64 * 232], Vlo[64 * 232];   // 59,392 B
  __shared__ __align__(16) unsigned short Ps[8][2][16 * 40];              // 20,480 B (per-wave hi/lo)
  __shared__ float gm8[8];

  const int bh = blockIdx.x;
  const int b = bh / NHEAD, h = bh % NHEAD;
  const float* base = qkv + (size_t)b * SEQ * NQKV;
  const int tid = threadIdx.x, lane = tid & 63, wv = tid >> 6;
  const int quad = lane >> 4, l16 = lane & 15;

  // ---- stage K (208 rows x 64, zero-padded rows) : coalesced float4 ----
  for (int idx = tid; idx < 208 * 16; idx += 512){
    int r = idx >> 4, c4 = (idx & 15) * 4;
    float4 v = {0.f, 0.f, 0.f, 0.f};
    if (r < SEQ) v = *(const float4*)(base + (size_t)r * NQKV + DMODEL + h * 64 + c4);
    unsigned short h0,l0,h1,l1,h2,l2,h3,l3;
    split_bf(v.x, h0, l0); split_bf(v.y, h1, l1); split_bf(v.z, h2, l2); split_bf(v.w, h3, l3);
    ushort4 hs = {h0, h1, h2, h3}, ls = {l0, l1, l2, l3};
    *(ushort4*)(Khi + r * 72 + c4) = hs;
    *(ushort4*)(Klo + r * 72 + c4) = ls;
  }
  // ---- stage V^T (64 rows x 232, cols >=196 zeroed) ----
  for (int idx = tid; idx < SEQ * 16; idx += 512){
    int s = idx >> 4, dg = (idx & 15) * 4;
    float4 v = *(const float4*)(base + (size_t)s * NQKV + 2 * DMODEL + h * 64 + dg);
    unsigned short hi, lo;
    split_bf(v.x, hi, lo); Vhi[(dg + 0) * 232 + s] = hi; Vlo[(dg + 0) * 232 + s] = lo;
    split_bf(v.y, hi, lo); Vhi[(dg + 1) * 232 + s] = hi; Vlo[(dg + 1) * 232 + s] = lo;
    split_bf(v.z, hi, lo); Vhi[(dg + 2) * 232 + s] = hi; Vlo[(dg + 2) * 232 + s] = lo;
    split_bf(v.w, hi, lo); Vhi[(dg + 3) * 232 + s] = hi; Vlo[(dg + 3) * 232 + s] = lo;
  }
  for (int idx = tid; idx < 64 * 36; idx += 512){
    int d = idx / 36, c = idx - d * 36;
    Vhi[d * 232 + SEQ + c] = 0; Vlo[d * 232 + SEQ + c] = 0;
  }
  __syncthreads();    // the ONLY full-block barrier in the main body

  unsigned short* PsH = &Ps[wv][0][0];
  unsigned short* PsL = &Ps[wv][1][0];

  float gmax = 0.f;
  for (int qt = wv; qt < 13; qt += 8){
    const int q0 = qt * 16;
    const int sq = q0 + l16;
    const bool valid = sq < SEQ;

    // Q fragments straight from global (A-layout: m=l16, k=quad*8+j), split hi/lo
    bf16x8 aqh[2], aql[2];
    const float* qrow = base + (size_t)(valid ? sq : 0) * NQKV + h * 64;
#pragma unroll
    for (int ks = 0; ks < 2; ks++){
      float4 v0 = {0,0,0,0}, v1 = {0,0,0,0};
      if (valid){
        v0 = *(const float4*)(qrow + ks * 32 + quad * 8);
        v1 = *(const float4*)(qrow + ks * 32 + quad * 8 + 4);
      }
      float vv[8] = {v0.x, v0.y, v0.z, v0.w, v1.x, v1.y, v1.z, v1.w};
#pragma unroll
      for (int j = 0; j < 8; j++){
        unsigned short hi, lo; split_bf(vv[j], hi, lo);
        aqh[ks][j] = (short)hi; aql[ks][j] = (short)lo;
      }
    }

    // ---- S = Q K^T / 8 : 13 independent MFMA chains ----
    f32x4 sacc[13];
#pragma unroll
    for (int t = 0; t < 13; t++){
      f32x4 a = {0.f, 0.f, 0.f, 0.f};
#pragma unroll
      for (int ks = 0; ks < 2; ks++){
        bf16x8 bkh = *(const bf16x8*)(Khi + (t * 16 + l16) * 72 + ks * 32 + quad * 8);
        bf16x8 bkl = *(const bf16x8*)(Klo + (t * 16 + l16) * 72 + ks * 32 + quad * 8);
        a = mfma16(aqh[ks], bkh, a);
        a = mfma16(aqh[ks], bkl, a);
        a = mfma16(aql[ks], bkh, a);
      }
      sacc[t] = a;
    }

    // ---- softmax in registers: lane holds rows q=quad*4+r, cols s=t*16+l16 ----
    float mx[4] = {-1e30f, -1e30f, -1e30f, -1e30f};
#pragma unroll
    for (int t = 0; t < 13; t++){
      bool dead = (t == 12) && (l16 >= 4);   // col >= 196
#pragma unroll
      for (int r = 0; r < 4; r++){
        float v = dead ? -1e30f : sacc[t][r] * 0.125f;
        sacc[t][r] = v;
        mx[r] = fmaxf(mx[r], v);
      }
    }
#pragma unroll
    for (int off = 1; off < 16; off <<= 1)
#pragma unroll
      for (int r = 0; r < 4; r++) mx[r] = fmaxf(mx[r], __shfl_xor(mx[r], off));
    float sum[4] = {0.f, 0.f, 0.f, 0.f};
#pragma unroll
    for (int t = 0; t < 13; t++)
#pragma unroll
      for (int r = 0; r < 4; r++){
        float e = __expf(sacc[t][r] - mx[r]);
        sacc[t][r] = e; sum[r] += e;
      }
#pragma unroll
    for (int off = 1; off < 16; off <<= 1)
#pragma unroll
      for (int r = 0; r < 4; r++) sum[r] += __shfl_xor(sum[r], off);
    float inv[4];
#pragma unroll
    for (int r = 0; r < 4; r++) inv[r] = 1.0f / sum[r];

    // ---- O = P V : per-ks transpose C->A layout through per-wave scratch, no barrier ----
    f32x4 oacc[4] = {};
#pragma unroll
    for (int ks = 0; ks < 7; ks++){
      const int t0 = 2 * ks, t1 = 2 * ks + 1;
#pragma unroll
      for (int r = 0; r < 4; r++){
        int row = quad * 4 + r;
        unsigned short hi, lo;
        split_bf(sacc[t0][r] * inv[r], hi, lo);
        PsH[row * 40 + l16] = hi; PsL[row * 40 + l16] = lo;
        if (t1 < 13){
          split_bf(sacc[t1][r] * inv[r], hi, lo);
          PsH[row * 40 + 16 + l16] = hi; PsL[row * 40 + 16 + l16] = lo;
        } else {
          PsH[row * 40 + 16 + l16] = 0; PsL[row * 40 + 16 + l16] = 0;
        }
      }
      __builtin_amdgcn_wave_barrier();   // keep compiler from reordering the RAW through LDS
      bf16x8 aph = *(const bf16x8*)(PsH + l16 * 40 + quad * 8);
      bf16x8 apl = *(const bf16x8*)(PsL + l16 * 40 + quad * 8);
#pragma unroll
      for (int n = 0; n < 4; n++){
        bf16x8 bvh = *(const bf16x8*)(Vhi + (n * 16 + l16) * 232 + ks * 32 + quad * 8);
        bf16x8 bvl = *(const bf16x8*)(Vlo + (n * 16 + l16) * 232 + ks * 32 + quad * 8);
        oacc[n] = mfma16(aph, bvh, oacc[n]);
        oacc[n] = mfma16(aph, bvl, oacc[n]);
        oacc[n] = mfma16(apl, bvh, oacc[n]);
      }
      __builtin_amdgcn_wave_barrier();   // reads of this slice complete before next-iter writes
    }

    // ---- store ctx (C-layout: row=quad*4+r, col=n*16+l16) + absmax ----
#pragma unroll
    for (int r = 0; r < 4; r++){
      int srow = q0 + quad * 4 + r;
      if (srow < SEQ){
#pragma unroll
        for (int n = 0; n < 4; n++){
          float v = oacc[n][r];
          ctx[((size_t)(b * SEQ + srow)) * DMODEL + h * 64 + n * 16 + l16] = v;
          gmax = fmaxf(gmax, fabsf(v));
        }
      }
    }
  }
  for (int off = 32; off; off >>= 1) gmax = fmaxf(gmax, __shfl_xor(gmax, off));
  if (lane == 0) gm8[wv] = gmax;
  __syncthreads();
  if (tid == 0){
    float bm = 0.f;
#pragma unroll
    for (int i = 0; i < 8; i++) bm = fmaxf(bm, gm8[i]);
    scatter_amax(slots, SL_CTX, blockIdx.x, bm);
  }
}

// ---------------- launch ----------------
extern "C" void kernel_launch(void* const* d_in, const int* in_sizes, int n_in,
                              void* d_out, int out_size, void* d_ws, size_t ws_size,
                              hipStream_t stream)
{
  const float* x     = (const float*)d_in[0];
  const float* ln1_g = (const float*)d_in[1];
  const float* ln1_b = (const float*)d_in[2];
  const float* ln2_g = (const float*)d_in[3];
  const float* ln2_b = (const float*)d_in[4];
  const float* w_qkv = (const float*)d_in[5];
  const float* b_qkv = (const float*)d_in[6];
  const float* w_o   = (const float*)d_in[7];
  const float* b_o   = (const float*)d_in[8];
  const float* w1    = (const float*)d_in[9];
  const float* b1    = (const float*)d_in[10];
  const float* w2    = (const float*)d_in[11];
  const float* b2    = (const float*)d_in[12];

  char* ws = (char*)d_ws;
  size_t off = 0;
  unsigned* slots = (unsigned*)ws;                 off += SLOTS_U32 * 4;   // 16 KB scattered slots
  char* wqkvT = (char*)(ws + off); off += (size_t)NQKV  * DMODEL;
  char* woT   = (char*)(ws + off); off += (size_t)DMODEL* DMODEL;
  char* w1T   = (char*)(ws + off); off += (size_t)MMLP  * DMODEL;
  char* w2T   = (char*)(ws + off); off += (size_t)DMODEL* MMLP;
  off = (off + 255) & ~(size_t)255;
  float* t1    = (float*)(ws + off);               off += (size_t)NTOK * DMODEL * 4;
  char*  t1q   = (char*)(ws + off);                off += (size_t)NTOK * DMODEL;
  off = (off + 255) & ~(size_t)255;
  float* qkv   = (float*)(ws + off);               off += (size_t)NTOK * NQKV * 4;
  float* xmid  = (float*)(ws + off);               off += (size_t)NTOK * DMODEL * 4;
  // FC1 bf16 output (77.07 MB) + its int8 quant (38.54 MB) exactly fill the qkv region (115.6 MB)
  unsigned short* h1 = (unsigned short*)qkv;
  char* h1q = (char*)qkv + (size_t)NTOK * MMLP * 2;
  float* outp = (float*)d_out;

  k_init<<<(SLOTS_U32 + 255) / 256, 256, 0, stream>>>(slots);

  k_absmax<<<256, 256, 0, stream>>>(w_qkv, DMODEL * NQKV / 4, slots, SL_WQKV);
  k_absmax<<<128, 256, 0, stream>>>(w_o,   DMODEL * DMODEL / 4, slots, SL_WO);
  k_absmax<<<256, 256, 0, stream>>>(w1,    DMODEL * MMLP / 4, slots, SL_W1);
  k_absmax<<<256, 256, 0, stream>>>(w2,    MMLP * DMODEL / 4, slots, SL_W2);

  k_quant_transpose<<<dim3(NQKV / 32, DMODEL / 32), 256, 0, stream>>>(w_qkv, wqkvT, DMODEL, NQKV, slots, SL_WQKV);
  k_quant_transpose<<<dim3(DMODEL / 32, DMODEL / 32), 256, 0, stream>>>(w_o, woT, DMODEL, DMODEL, slots, SL_WO);
  k_quant_transpose<<<dim3(MMLP / 32, DMODEL / 32), 256, 0, stream>>>(w1, w1T, DMODEL, MMLP, slots, SL_W1);
  k_quant_transpose<<<dim3(DMODEL / 32, MMLP / 32), 256, 0, stream>>>(w2, w2T, MMLP, DMODEL, slots, SL_W2);

  // LN1 -> quant -> QKV
  k_layernorm<<<NTOK / 4, 256, 0, stream>>>(x, ln1_g, ln1_b, t1, slots, SL_LN1);
  {
    int n4 = NTOK * DMODEL / 4;
    k_quant_act<<<(n4 + 255) / 256, 256, 0, stream>>>(t1, (unsigned*)t1q, n4, slots, SL_LN1);
  }
  k_gemm<0><<<dim3(NQKV / 128, NTOK / 128), 256, 0, stream>>>(
      t1q, wqkvT, b_qkv, nullptr, qkv, nullptr, slots, SL_LN1, SL_WQKV, nullptr, 0,
      NTOK, NQKV, DMODEL);

  // attention -> ctx (t1) + absmax
  k_attention<<<NBATCH * NHEAD, 512, 0, stream>>>(qkv, t1, slots);
  {
    int n4 = NTOK * DMODEL / 4;
    k_quant_act<<<(n4 + 255) / 256, 256, 0, stream>>>(t1, (unsigned*)t1q, n4, slots, SL_CTX);
  }
  // O-proj + residual -> xmid
  k_gemm<1><<<dim3(DMODEL / 128, NTOK / 128), 256, 0, stream>>>(
      t1q, woT, b_o, x, xmid, nullptr, slots, SL_CTX, SL_WO, nullptr, 0,
      NTOK, DMODEL, DMODEL);

  // LN2 -> quant -> FC1(+gelu->bf16) -> quant -> FC2 + residual -> out
  k_layernorm<<<NTOK / 4, 256, 0, stream>>>(xmid, ln2_g, ln2_b, t1, slots, SL_LN2);
  {
    int n4 = NTOK * DMODEL / 4;
    k_quant_act<<<(n4 + 255) / 256, 256, 0, stream>>>(t1, (unsigned*)t1q, n4, slots, SL_LN2);
  }
  k_gemm<2><<<dim3(MMLP / 128, NTOK / 128), 256, 0, stream>>>(
      t1q, w1T, b1, nullptr, nullptr, h1, slots, SL_LN2, SL_W1, slots, SL_GELU,
      NTOK, MMLP, DMODEL);
  {
    int n4 = NTOK * MMLP / 4;
    k_quant_bf16_i8<<<(n4 + 255) / 256, 256, 0, stream>>>(h1, (unsigned*)h1q, n4, slots, SL_GELU);
  }
  k_gemm<1><<<dim3(DMODEL / 128, NTOK / 128), 256, 0, stream>>>(
      h1q, w2T, b2, xmid, outp, nullptr, slots, SL_GELU, SL_W2, nullptr, 0,
      NTOK, DMODEL, MMLP);
}

// Round 3
// 500.894 us; speedup vs baseline: 1.7338x; 1.0284x over previous
//
#include <hip/hip_runtime.h>
#include <cstdint>
#include <cstddef>

#define DEVFN __device__ __forceinline__

typedef short bf16x8 __attribute__((ext_vector_type(8)));
typedef float f32x4  __attribute__((ext_vector_type(4)));
typedef int   i32x4  __attribute__((ext_vector_type(4)));

// problem constants
static constexpr int NTOK  = 64 * 196;   // 12544  (= 98 * 128)
static constexpr int DMODEL= 768;
static constexpr int NHEAD = 12;
static constexpr int NQKV  = 2304;       // 3*768 (= 18 * 128)
static constexpr int MMLP  = 3072;       // 4*768 (= 24 * 128)
static constexpr int SEQ   = 196;
static constexpr int NBATCH= 64;

// scale slots (absmax bits, atomicMax on uint reinterpretation of fp32)
enum { SL_LN1=0, SL_WQKV=1, SL_CTX=2, SL_WO=3, SL_LN2=4, SL_W1=5, SL_GELU=6, SL_W2=7 };

// ---- scattered absmax slots: 64 shadow copies per logical slot, 256B apart ----
static constexpr int NSH       = 64;     // shadow buckets per slot
static constexpr int SH_STRIDE = 64;     // uints between buckets (256 B lines)
static constexpr int SLOTS_U32 = NSH * SH_STRIDE;   // 4096 uints = 16 KB

DEVFN float bf2f(unsigned short u){ return __uint_as_float(((unsigned)u) << 16); }
DEVFN unsigned short f2bf(float f){            // round-to-nearest-even
  unsigned u = __float_as_uint(f);
  u += 0x7fffu + ((u >> 16) & 1u);
  return (unsigned short)(u >> 16);
}
DEVFN void split_bf(float v, unsigned short& hi, unsigned short& lo){
  hi = f2bf(v);
  lo = f2bf(v - bf2f(hi));                     // v-hi is exact in fp32
}
DEVFN float slot_absmax(const unsigned* __restrict__ slots, int slot){
  unsigned m = 0u;
#pragma unroll
  for (int j = 0; j < NSH; j++){
    unsigned u = slots[j * SH_STRIDE + slot];  // uniform scalar loads, L2-hot
    m = (u > m) ? u : m;                       // bits >=0: uint order == float order
  }
  return __uint_as_float(m);
}
DEVFN float slot_scale(const unsigned* __restrict__ slots, int slot){
  return fmaxf(slot_absmax(slots, slot) / 127.0f, 1e-8f);   // exact match to ref: max/127.0
}
DEVFN void scatter_amax(unsigned* slots, int slot, unsigned bucket, float v){
  atomicMax(slots + (bucket & (NSH - 1)) * SH_STRIDE + slot, __float_as_uint(v));
}
DEVFN float quantval(float x, float s){        // integer-valued quantized result
  float q = rintf(x / s);                      // RNE, matches jnp.round
  return fminf(fmaxf(q, -128.0f), 127.0f);
}
DEVFN unsigned pack4(float a, float b, float c, float d){
  return  ((unsigned)(unsigned char)(char)(int)a)
        | ((unsigned)(unsigned char)(char)(int)b << 8)
        | ((unsigned)(unsigned char)(char)(int)c << 16)
        | ((unsigned)(unsigned char)(char)(int)d << 24);
}
// exact-GELU with branch-free A&S 7.1.26 erf (max abs err 1.5e-7, invisible
// under the immediate bf16 rounding of the result).
DEVFN float gelu_fast(float v){
  float s  = v * 0.70710678118654752f;
  float ax = fabsf(s);
  float t  = __builtin_amdgcn_rcpf(fmaf(0.3275911f, ax, 1.0f));
  float p  = t * fmaf(t, fmaf(t, fmaf(t, fmaf(t, 1.061405429f, -1.453152027f),
                                      1.421413741f), -0.284496736f), 0.254829592f);
  float er = fmaf(-p, __expf(-ax * ax), 1.0f);           // erf(|s|) in [0,1)
  unsigned sgn = __float_as_uint(s) & 0x80000000u;
  er = __uint_as_float(__float_as_uint(er) | sgn);
  return 0.5f * v * (1.0f + er);
}
DEVFN f32x4 mfma16(bf16x8 a, bf16x8 b, f32x4 c){
  return __builtin_amdgcn_mfma_f32_16x16x32_bf16(a, b, c, 0, 0, 0);
}
DEVFN i32x4 mfma16i8(i32x4 a, i32x4 b, i32x4 c){
  return __builtin_amdgcn_mfma_i32_16x16x64_i8(a, b, c, 0, 0, 0);
}
DEVFN void async_ld16(const void* g, void* lds){
  __builtin_amdgcn_global_load_lds((const __attribute__((address_space(1))) void*)g,
                                   (__attribute__((address_space(3))) void*)lds, 16, 0, 0);
}
// V^T LDS layout: stride 256 ushorts + XOR swizzle on s-bits 3..5.
// Writes (d varying by 4 per lane) spread across 8 bank-groups; 16B reads stay
// aligned & uniform (swizzle only permutes 16B chunks within a 512B row).
DEVFN int vidx(int d, int s){
  return d * 256 + (s ^ (((d ^ (d >> 2)) & 7) << 3));
}

// ---------------- init scale slots ----------------
__global__ void k_init(unsigned* slots){
  int i = blockIdx.x * blockDim.x + threadIdx.x;
  if (i < SLOTS_U32) slots[i] = 0u;
}

// ---------------- fused absmax of the 4 weight tensors (1 launch) ----------------
__global__ void k_absmax4(const float* __restrict__ x0, const float* __restrict__ x1,
                          const float* __restrict__ x2, const float* __restrict__ x3,
                          unsigned* slots){
  int bid = blockIdx.x;
  const float* x; int n4, slot, b0, nb;
  if (bid < 256)      { x = x0; n4 = DMODEL * NQKV  / 4; slot = SL_WQKV; b0 = 0;   nb = 256; }
  else if (bid < 384) { x = x1; n4 = DMODEL * DMODEL/ 4; slot = SL_WO;   b0 = 256; nb = 128; }
  else if (bid < 640) { x = x2; n4 = DMODEL * MMLP  / 4; slot = SL_W1;   b0 = 384; nb = 256; }
  else                { x = x3; n4 = MMLP   * DMODEL/ 4; slot = SL_W2;   b0 = 640; nb = 256; }
  int lb = bid - b0;
  float m = 0.f;
  const float4* x4 = (const float4*)x;
  int stride = nb * blockDim.x;
  for (int j = lb * blockDim.x + threadIdx.x; j < n4; j += stride){
    float4 v = x4[j];
    m = fmaxf(m, fmaxf(fmaxf(fabsf(v.x), fabsf(v.y)), fmaxf(fabsf(v.z), fabsf(v.w))));
  }
  for (int off = 32; off; off >>= 1) m = fmaxf(m, __shfl_xor(m, off));
  __shared__ float wm[4];
  int lane = threadIdx.x & 63, w = threadIdx.x >> 6;
  if (lane == 0) wm[w] = m;
  __syncthreads();
  if (threadIdx.x == 0){
    float bm = fmaxf(fmaxf(wm[0], wm[1]), fmaxf(wm[2], wm[3]));
    scatter_amax(slots, slot, bid, bm);
  }
}

// ---------------- quantize weight (K x N fp32) -> transposed int8 (N x K) ----------------
__global__ void k_quant_transpose(const float* __restrict__ w, char* __restrict__ wt,
                                  int K, int N, const unsigned* __restrict__ slots, int slot){
  __shared__ float tile[32][33];
  float s = slot_scale(slots, slot);
  int n0 = blockIdx.x * 32, k0 = blockIdx.y * 32;
  int tx = threadIdx.x & 31, ty = threadIdx.x >> 5;   // 256 threads: ty 0..7
#pragma unroll
  for (int i = 0; i < 4; i++){
    int k = k0 + ty + i * 8;
    float v = w[(size_t)k * N + n0 + tx];
    tile[ty + i * 8][tx] = quantval(v, s);
  }
  __syncthreads();
  // write: thread -> (n = tid>>3, kg = tid&7), 4 consecutive k bytes
  int n = threadIdx.x >> 3, kg = threadIdx.x & 7;
  unsigned o = pack4(tile[kg * 4 + 0][n], tile[kg * 4 + 1][n],
                     tile[kg * 4 + 2][n], tile[kg * 4 + 3][n]);
  *(unsigned*)(wt + (size_t)(n0 + n) * K + k0 + kg * 4) = o;
}

// ---------------- layernorm (rows of 768) + absmax ----------------
__global__ void k_layernorm(const float* __restrict__ x, const float* __restrict__ g,
                            const float* __restrict__ b, float* __restrict__ out,
                            unsigned* slots, int slot){
  int w = threadIdx.x >> 6, lane = threadIdx.x & 63;
  int row = blockIdx.x * 4 + w;
  const float4* xr = (const float4*)(x + (size_t)row * DMODEL);
  float4 v[3];
  float sum = 0.f;
#pragma unroll
  for (int i = 0; i < 3; i++){ v[i] = xr[i * 64 + lane]; sum += v[i].x + v[i].y + v[i].z + v[i].w; }
  for (int off = 32; off; off >>= 1) sum += __shfl_xor(sum, off);
  float mu = sum * (1.0f / 768.0f);
  float vs = 0.f;
#pragma unroll
  for (int i = 0; i < 3; i++){
    float dx = v[i].x - mu, dy = v[i].y - mu, dz = v[i].z - mu, dw = v[i].w - mu;
    vs += dx * dx + dy * dy + dz * dz + dw * dw;
  }
  for (int off = 32; off; off >>= 1) vs += __shfl_xor(vs, off);
  float inv = 1.0f / sqrtf(vs * (1.0f / 768.0f) + 1e-5f);
  const float4* g4 = (const float4*)g; const float4* b4 = (const float4*)b;
  float4* o4 = (float4*)(out + (size_t)row * DMODEL);
  float am = 0.f;
#pragma unroll
  for (int i = 0; i < 3; i++){
    float4 gg = g4[i * 64 + lane], bb = b4[i * 64 + lane], o;
    o.x = (v[i].x - mu) * inv * gg.x + bb.x;
    o.y = (v[i].y - mu) * inv * gg.y + bb.y;
    o.z = (v[i].z - mu) * inv * gg.z + bb.z;
    o.w = (v[i].w - mu) * inv * gg.w + bb.w;
    am = fmaxf(am, fmaxf(fmaxf(fabsf(o.x), fabsf(o.y)), fmaxf(fabsf(o.z), fabsf(o.w))));
    o4[i * 64 + lane] = o;
  }
  for (int off = 32; off; off >>= 1) am = fmaxf(am, __shfl_xor(am, off));
  __shared__ float am4[4];
  if (lane == 0) am4[w] = am;
  __syncthreads();
  if (threadIdx.x == 0){
    float bm = fmaxf(fmaxf(am4[0], am4[1]), fmaxf(am4[2], am4[3]));
    scatter_amax(slots, slot, blockIdx.x, bm);
  }
}

// ---------------- quantize fp32 activations -> packed int8 ----------------
__global__ void k_quant_act(const float* __restrict__ x, unsigned* __restrict__ out,
                            int n4, const unsigned* __restrict__ slots, int slot){
  float s = slot_scale(slots, slot);
  const float4* x4 = (const float4*)x;
  int stride = gridDim.x * blockDim.x;
  for (int j = blockIdx.x * blockDim.x + threadIdx.x; j < n4; j += stride){
    float4 v = x4[j];
    out[j] = pack4(quantval(v.x, s), quantval(v.y, s), quantval(v.z, s), quantval(v.w, s));
  }
}

// ---------------- quantize bf16 activations -> packed int8 ----------------
__global__ void k_quant_bf16_i8(const unsigned short* __restrict__ x, unsigned* __restrict__ out,
                                int n4, const unsigned* __restrict__ slots, int slot){
  float s = slot_scale(slots, slot);
  const ushort4* x4 = (const ushort4*)x;
  int stride = gridDim.x * blockDim.x;
  for (int j = blockIdx.x * blockDim.x + threadIdx.x; j < n4; j += stride){
    ushort4 v = x4[j];
    out[j] = pack4(quantval(bf2f(v.x), s), quantval(bf2f(v.y), s),
                   quantval(bf2f(v.z), s), quantval(bf2f(v.w), s));
  }
}

// ---------------- int8 GEMM: C[M,N] = sa*sb * (A[M,K] @ Bt[N,K]^T) + bias (+res / gelu) ---------
// mfma_i32_16x16x64_i8, BK=64, DOUBLE-BUFFERED staging with raw s_barrier + partial vmcnt.
// LDS tiles chunk-rotated (applied on the per-lane GLOBAL source address) so fragment
// ds_read_b128s are bank-conflict-free.
// EPI 0: fp32 (bias) | 1: fp32 (bias+res) | 2: gelu -> absmax -> bf16
template<int EPI>
__launch_bounds__(256, 4)
__global__ void k_gemm(const char* __restrict__ A,    // M x K int8
                       const char* __restrict__ Bt,   // N x K int8
                       const float* __restrict__ bias,
                       const float* __restrict__ res,
                       float* __restrict__ Cf,
                       unsigned short* __restrict__ Cb,
                       const unsigned* __restrict__ slots, int sa_slot, int sb_slot,
                       unsigned* gmax_slots, int gmax_slot,
                       int M, int N, int K)
{
  __shared__ __align__(16) char smem[32768];
  __shared__ float gm4[4];
  const int tid  = threadIdx.x;
  const int lane = tid & 63;
  const int wv   = tid >> 6;        // 0..3
  const int wx   = wv & 1, wy = wv >> 1;
  const int quad = lane >> 4;
  const int l16  = lane & 15;
  const int m0 = blockIdx.y * 128, n0 = blockIdx.x * 128;

  auto issue = [&](int k0, int buf){
#pragma unroll
    for (int i = 0; i < 2; i++){     // A tile: 512 chunks of 16B (row = c>>2, q = c&3)
      int c = tid + i * 256;
      int row = c >> 2, q = c & 3;
      int qs = (q - ((row + (row >> 2)) & 3)) & 3;   // inverse chunk rotation
      async_ld16(A + (size_t)(m0 + row) * K + k0 + qs * 16,
                 smem + buf * 8192 + (i * 256 + wv * 64) * 16);
    }
#pragma unroll
    for (int i = 0; i < 2; i++){     // B tile
      int c = tid + i * 256;
      int row = c >> 2, q = c & 3;
      int qs = (q - ((row + (row >> 2)) & 3)) & 3;
      async_ld16(Bt + (size_t)(n0 + row) * K + k0 + qs * 16,
                 smem + 16384 + buf * 8192 + (i * 256 + wv * 64) * 16);
    }
  };

  i32x4 acc[4][4] = {};
  const int nk = K >> 6;
  issue(0, 0);

  const int ch = (((quad + (l16 & 3) + (l16 >> 2)) & 3)) * 16;

  for (int k = 0; k < nk; k++){
    const int cur = k & 1;
    if (k + 1 < nk){
      issue((k + 1) << 6, cur ^ 1);                       // prefetch next tile
      asm volatile("s_waitcnt vmcnt(4)" ::: "memory");    // tile-k loads landed; k+1 in flight
    } else {
      asm volatile("s_waitcnt vmcnt(0)" ::: "memory");
    }
    asm volatile("s_barrier" ::: "memory");               // tile-k visible to all waves

    const char* Ab = smem + cur * 8192;
    const char* Bb = smem + 16384 + cur * 8192;
    i32x4 af[4], bfr[4];
#pragma unroll
    for (int i = 0; i < 4; i++)
      af[i] = *(const i32x4*)(Ab + (wy * 64 + i * 16 + l16) * 64 + ch);
#pragma unroll
    for (int j = 0; j < 4; j++)
      bfr[j] = *(const i32x4*)(Bb + (wx * 64 + j * 16 + l16) * 64 + ch);
    asm volatile("s_waitcnt lgkmcnt(0)" ::: "memory");    // frags in regs
    asm volatile("s_barrier" ::: "memory");               // all reads of cur done

#pragma unroll
    for (int i = 0; i < 4; i++)
#pragma unroll
      for (int j = 0; j < 4; j++)
        acc[i][j] = mfma16i8(af[i], bfr[j], acc[i][j]);
  }
  __syncthreads();   // all waves out of the K-loop before stage overlay is used

  // ---- epilogue: 4 slices of 32 rows; LDS transpose -> coalesced wide loads/stores ----
  float (*stage)[132] = (float (*)[132])smem;   // 16896 B, overlays dead tile buffers
  const float sc = slot_scale(slots, sa_slot) * slot_scale(slots, sb_slot);
  const int col4 = (tid & 31) * 4;           // 0..124
  const int gc   = n0 + col4;
  const float4 bb = *(const float4*)&bias[gc];
  float gmax = 0.f;
#pragma unroll
  for (int i = 0; i < 4; i++){
#pragma unroll
    for (int j = 0; j < 4; j++)
#pragma unroll
      for (int r = 0; r < 4; r++)
        stage[wy * 16 + quad * 4 + r][wx * 64 + j * 16 + l16] = (float)acc[i][j][r];
    __syncthreads();
#pragma unroll
    for (int rr = 0; rr < 4; rr++){
      const int rl = rr * 8 + (tid >> 5);                       // 0..31
      const int gm = m0 + ((rl >> 4) * 64) + i * 16 + (rl & 15);
      float4 v = *(const float4*)&stage[rl][col4];
      v.x = v.x * sc + bb.x; v.y = v.y * sc + bb.y;
      v.z = v.z * sc + bb.z; v.w = v.w * sc + bb.w;
      if constexpr (EPI == 1){
        float4 rv = *(const float4*)&res[(size_t)gm * N + gc];
        v.x += rv.x; v.y += rv.y; v.z += rv.z; v.w += rv.w;
        *(float4*)&Cf[(size_t)gm * N + gc] = v;
      } else if constexpr (EPI == 2){
        float g0 = gelu_fast(v.x);
        float g1 = gelu_fast(v.y);
        float g2 = gelu_fast(v.z);
        float g3 = gelu_fast(v.w);
        gmax = fmaxf(gmax, fmaxf(fmaxf(fabsf(g0), fabsf(g1)), fmaxf(fabsf(g2), fabsf(g3))));
        ushort4 o = {f2bf(g0), f2bf(g1), f2bf(g2), f2bf(g3)};
        *(ushort4*)&Cb[(size_t)gm * N + gc] = o;
      } else {
        *(float4*)&Cf[(size_t)gm * N + gc] = v;
      }
    }
    __syncthreads();
  }
  if constexpr (EPI == 2){
    for (int off = 32; off; off >>= 1) gmax = fmaxf(gmax, __shfl_xor(gmax, off));
    if (lane == 0) gm4[wv] = gmax;
    __syncthreads();
    if (tid == 0){
      float bm = fmaxf(fmaxf(gm4[0], gm4[1]), fmaxf(gm4[2], gm4[3]));
      scatter_amax(gmax_slots, gmax_slot, blockIdx.x + blockIdx.y * gridDim.x, bm);
    }
  }
}

// ---------------- attention: one block per (b,h), 8 waves, barrier-free main loop --------------
__launch_bounds__(512, 2)
__global__ void k_attention(const float* __restrict__ qkv, float* __restrict__ ctx,
                            unsigned* slots){
  __shared__ __align__(16) unsigned short Khi[208 * 72], Klo[208 * 72];   // 59,904 B
  __shared__ __align__(16) unsigned short Vhi[64 * 256], Vlo[64 * 256];   // 65,536 B (swizzled)
  __shared__ __align__(16) unsigned short Ps[8][2][16 * 40];              // 20,480 B (per-wave hi/lo)
  __shared__ float gm8[8];

  const int bh = blockIdx.x;
  const int b = bh / NHEAD, h = bh % NHEAD;
  const float* base = qkv + (size_t)b * SEQ * NQKV;
  const int tid = threadIdx.x, lane = tid & 63, wv = tid >> 6;
  const int quad = lane >> 4, l16 = lane & 15;

  // ---- prefetch ALL K/V global data into registers first (hide HBM latency
  // under the split_bf conversion work), then convert+write LDS ----
  float4 kreg[7], vreg[8];
#pragma unroll
  for (int i = 0; i < 7; i++){
    int idx = tid + i * 512;                  // K: 208*16 = 3328 chunks
    int r = idx >> 4, c4 = (idx & 15) * 4;
    float4 v = {0.f, 0.f, 0.f, 0.f};
    if (idx < 208 * 16 && r < SEQ)
      v = *(const float4*)(base + (size_t)r * NQKV + DMODEL + h * 64 + c4);
    kreg[i] = v;
  }
#pragma unroll
  for (int i = 0; i < 8; i++){
    int idx = tid + i * 512;                  // V: 232*16 = 3712 chunks (incl. zero pad)
    int s = idx >> 4, dg = (idx & 15) * 4;
    float4 v = {0.f, 0.f, 0.f, 0.f};
    if (idx < 232 * 16 && s < SEQ)
      v = *(const float4*)(base + (size_t)s * NQKV + 2 * DMODEL + h * 64 + dg);
    vreg[i] = v;
  }
  // ---- K (208 rows x 64, zero-padded rows), row stride 72 ----
#pragma unroll
  for (int i = 0; i < 7; i++){
    int idx = tid + i * 512;
    if (idx < 208 * 16){
      int r = idx >> 4, c4 = (idx & 15) * 4;
      float4 v = kreg[i];
      unsigned short h0,l0,h1,l1,h2,l2,h3,l3;
      split_bf(v.x, h0, l0); split_bf(v.y, h1, l1); split_bf(v.z, h2, l2); split_bf(v.w, h3, l3);
      ushort4 hs = {h0, h1, h2, h3}, ls = {l0, l1, l2, l3};
      *(ushort4*)(Khi + r * 72 + c4) = hs;
      *(ushort4*)(Klo + r * 72 + c4) = ls;
    }
  }
  // ---- V^T (64 rows x 256, swizzled; s>=196 zeroed via the same pass) ----
#pragma unroll
  for (int i = 0; i < 8; i++){
    int idx = tid + i * 512;
    if (idx < 232 * 16){
      int s = idx >> 4, dg = (idx & 15) * 4;
      float4 v = vreg[i];
      unsigned short hi, lo;
      split_bf(v.x, hi, lo); Vhi[vidx(dg + 0, s)] = hi; Vlo[vidx(dg + 0, s)] = lo;
      split_bf(v.y, hi, lo); Vhi[vidx(dg + 1, s)] = hi; Vlo[vidx(dg + 1, s)] = lo;
      split_bf(v.z, hi, lo); Vhi[vidx(dg + 2, s)] = hi; Vlo[vidx(dg + 2, s)] = lo;
      split_bf(v.w, hi, lo); Vhi[vidx(dg + 3, s)] = hi; Vlo[vidx(dg + 3, s)] = lo;
    }
  }
  __syncthreads();    // the ONLY full-block barrier in the main body

  unsigned short* PsH = &Ps[wv][0][0];
  unsigned short* PsL = &Ps[wv][1][0];

  float gmax = 0.f;
  for (int qt = wv; qt < 13; qt += 8){
    const int q0 = qt * 16;
    const int sq = q0 + l16;
    const bool valid = sq < SEQ;

    // Q fragments straight from global (A-layout: m=l16, k=quad*8+j), split hi/lo
    bf16x8 aqh[2], aql[2];
    const float* qrow = base + (size_t)(valid ? sq : 0) * NQKV + h * 64;
#pragma unroll
    for (int ks = 0; ks < 2; ks++){
      float4 v0 = {0,0,0,0}, v1 = {0,0,0,0};
      if (valid){
        v0 = *(const float4*)(qrow + ks * 32 + quad * 8);
        v1 = *(const float4*)(qrow + ks * 32 + quad * 8 + 4);
      }
      float vv[8] = {v0.x, v0.y, v0.z, v0.w, v1.x, v1.y, v1.z, v1.w};
#pragma unroll
      for (int j = 0; j < 8; j++){
        unsigned short hi, lo; split_bf(vv[j], hi, lo);
        aqh[ks][j] = (short)hi; aql[ks][j] = (short)lo;
      }
    }

    // ---- S = Q K^T / 8 : 13 independent MFMA chains ----
    f32x4 sacc[13];
#pragma unroll
    for (int t = 0; t < 13; t++){
      f32x4 a = {0.f, 0.f, 0.f, 0.f};
#pragma unroll
      for (int ks = 0; ks < 2; ks++){
        bf16x8 bkh = *(const bf16x8*)(Khi + (t * 16 + l16) * 72 + ks * 32 + quad * 8);
        bf16x8 bkl = *(const bf16x8*)(Klo + (t * 16 + l16) * 72 + ks * 32 + quad * 8);
        a = mfma16(aqh[ks], bkh, a);
        a = mfma16(aqh[ks], bkl, a);
        a = mfma16(aql[ks], bkh, a);
      }
      sacc[t] = a;
    }

    // ---- softmax in registers: lane holds rows q=quad*4+r, cols s=t*16+l16 ----
    float mx[4] = {-1e30f, -1e30f, -1e30f, -1e30f};
#pragma unroll
    for (int t = 0; t < 13; t++){
      bool dead = (t == 12) && (l16 >= 4);   // col >= 196
#pragma unroll
      for (int r = 0; r < 4; r++){
        float v = dead ? -1e30f : sacc[t][r] * 0.125f;
        sacc[t][r] = v;
        mx[r] = fmaxf(mx[r], v);
      }
    }
#pragma unroll
    for (int off = 1; off < 16; off <<= 1)
#pragma unroll
      for (int r = 0; r < 4; r++) mx[r] = fmaxf(mx[r], __shfl_xor(mx[r], off));
    float sum[4] = {0.f, 0.f, 0.f, 0.f};
#pragma unroll
    for (int t = 0; t < 13; t++)
#pragma unroll
      for (int r = 0; r < 4; r++){
        float e = __expf(sacc[t][r] - mx[r]);
        sacc[t][r] = e; sum[r] += e;
      }
#pragma unroll
    for (int off = 1; off < 16; off <<= 1)
#pragma unroll
      for (int r = 0; r < 4; r++) sum[r] += __shfl_xor(sum[r], off);
    float inv[4];
#pragma unroll
    for (int r = 0; r < 4; r++) inv[r] = 1.0f / sum[r];

    // ---- O = P V : per-ks transpose C->A layout through per-wave scratch, no barrier ----
    f32x4 oacc[4] = {};
#pragma unroll
    for (int ks = 0; ks < 7; ks++){
      const int t0 = 2 * ks, t1 = 2 * ks + 1;
#pragma unroll
      for (int r = 0; r < 4; r++){
        int row = quad * 4 + r;
        unsigned short hi, lo;
        split_bf(sacc[t0][r] * inv[r], hi, lo);
        PsH[row * 40 + l16] = hi; PsL[row * 40 + l16] = lo;
        if (t1 < 13){
          split_bf(sacc[t1][r] * inv[r], hi, lo);
          PsH[row * 40 + 16 + l16] = hi; PsL[row * 40 + 16 + l16] = lo;
        } else {
          PsH[row * 40 + 16 + l16] = 0; PsL[row * 40 + 16 + l16] = 0;
        }
      }
      __builtin_amdgcn_wave_barrier();   // keep compiler from reordering the RAW through LDS
      bf16x8 aph = *(const bf16x8*)(PsH + l16 * 40 + quad * 8);
      bf16x8 apl = *(const bf16x8*)(PsL + l16 * 40 + quad * 8);
#pragma unroll
      for (int n = 0; n < 4; n++){
        bf16x8 bvh = *(const bf16x8*)(Vhi + vidx(n * 16 + l16, ks * 32 + quad * 8));
        bf16x8 bvl = *(const bf16x8*)(Vlo + vidx(n * 16 + l16, ks * 32 + quad * 8));
        oacc[n] = mfma16(aph, bvh, oacc[n]);
        oacc[n] = mfma16(aph, bvl, oacc[n]);
        oacc[n] = mfma16(apl, bvh, oacc[n]);
      }
      __builtin_amdgcn_wave_barrier();   // reads of this slice complete before next-iter writes
    }

    // ---- store ctx (C-layout: row=quad*4+r, col=n*16+l16) + absmax ----
#pragma unroll
    for (int r = 0; r < 4; r++){
      int srow = q0 + quad * 4 + r;
      if (srow < SEQ){
#pragma unroll
        for (int n = 0; n < 4; n++){
          float v = oacc[n][r];
          ctx[((size_t)(b * SEQ + srow)) * DMODEL + h * 64 + n * 16 + l16] = v;
          gmax = fmaxf(gmax, fabsf(v));
        }
      }
    }
  }
  for (int off = 32; off; off >>= 1) gmax = fmaxf(gmax, __shfl_xor(gmax, off));
  if (lane == 0) gm8[wv] = gmax;
  __syncthreads();
  if (tid == 0){
    float bm = 0.f;
#pragma unroll
    for (int i = 0; i < 8; i++) bm = fmaxf(bm, gm8[i]);
    scatter_amax(slots, SL_CTX, blockIdx.x, bm);
  }
}

// ---------------- launch ----------------
extern "C" void kernel_launch(void* const* d_in, const int* in_sizes, int n_in,
                              void* d_out, int out_size, void* d_ws, size_t ws_size,
                              hipStream_t stream)
{
  const float* x     = (const float*)d_in[0];
  const float* ln1_g = (const float*)d_in[1];
  const float* ln1_b = (const float*)d_in[2];
  const float* ln2_g = (const float*)d_in[3];
  const float* ln2_b = (const float*)d_in[4];
  const float* w_qkv = (const float*)d_in[5];
  const float* b_qkv = (const float*)d_in[6];
  const float* w_o   = (const float*)d_in[7];
  const float* b_o   = (const float*)d_in[8];
  const float* w1    = (const float*)d_in[9];
  const float* b1    = (const float*)d_in[10];
  const float* w2    = (const float*)d_in[11];
  const float* b2    = (const float*)d_in[12];

  char* ws = (char*)d_ws;
  size_t off = 0;
  unsigned* slots = (unsigned*)ws;                 off += SLOTS_U32 * 4;   // 16 KB scattered slots
  char* wqkvT = (char*)(ws + off); off += (size_t)NQKV  * DMODEL;
  char* woT   = (char*)(ws + off); off += (size_t)DMODEL* DMODEL;
  char* w1T   = (char*)(ws + off); off += (size_t)MMLP  * DMODEL;
  char* w2T   = (char*)(ws + off); off += (size_t)DMODEL* MMLP;
  off = (off + 255) & ~(size_t)255;
  float* t1    = (float*)(ws + off);               off += (size_t)NTOK * DMODEL * 4;
  char*  t1q   = (char*)(ws + off);                off += (size_t)NTOK * DMODEL;
  off = (off + 255) & ~(size_t)255;
  float* qkv   = (float*)(ws + off);               off += (size_t)NTOK * NQKV * 4;
  float* xmid  = (float*)(ws + off);               off += (size_t)NTOK * DMODEL * 4;
  // FC1 bf16 output (77.07 MB) + its int8 quant (38.54 MB) exactly fill the qkv region (115.6 MB)
  unsigned short* h1 = (unsigned short*)qkv;
  char* h1q = (char*)qkv + (size_t)NTOK * MMLP * 2;
  float* outp = (float*)d_out;

  k_init<<<(SLOTS_U32 + 255) / 256, 256, 0, stream>>>(slots);

  k_absmax4<<<896, 256, 0, stream>>>(w_qkv, w_o, w1, w2, slots);

  k_quant_transpose<<<dim3(NQKV / 32, DMODEL / 32), 256, 0, stream>>>(w_qkv, wqkvT, DMODEL, NQKV, slots, SL_WQKV);
  k_quant_transpose<<<dim3(DMODEL / 32, DMODEL / 32), 256, 0, stream>>>(w_o, woT, DMODEL, DMODEL, slots, SL_WO);
  k_quant_transpose<<<dim3(MMLP / 32, DMODEL / 32), 256, 0, stream>>>(w1, w1T, DMODEL, MMLP, slots, SL_W1);
  k_quant_transpose<<<dim3(DMODEL / 32, MMLP / 32), 256, 0, stream>>>(w2, w2T, MMLP, DMODEL, slots, SL_W2);

  // LN1 -> quant -> QKV
  k_layernorm<<<NTOK / 4, 256, 0, stream>>>(x, ln1_g, ln1_b, t1, slots, SL_LN1);
  {
    int n4 = NTOK * DMODEL / 4;
    k_quant_act<<<(n4 + 255) / 256, 256, 0, stream>>>(t1, (unsigned*)t1q, n4, slots, SL_LN1);
  }
  k_gemm<0><<<dim3(NQKV / 128, NTOK / 128), 256, 0, stream>>>(
      t1q, wqkvT, b_qkv, nullptr, qkv, nullptr, slots, SL_LN1, SL_WQKV, nullptr, 0,
      NTOK, NQKV, DMODEL);

  // attention -> ctx (t1) + absmax
  k_attention<<<NBATCH * NHEAD, 512, 0, stream>>>(qkv, t1, slots);
  {
    int n4 = NTOK * DMODEL / 4;
    k_quant_act<<<(n4 + 255) / 256, 256, 0, stream>>>(t1, (unsigned*)t1q, n4, slots, SL_CTX);
  }
  // O-proj + residual -> xmid
  k_gemm<1><<<dim3(DMODEL / 128, NTOK / 128), 256, 0, stream>>>(
      t1q, woT, b_o, x, xmid, nullptr, slots, SL_CTX, SL_WO, nullptr, 0,
      NTOK, DMODEL, DMODEL);

  // LN2 -> quant -> FC1(+gelu->bf16) -> quant -> FC2 + residual -> out
  k_layernorm<<<NTOK / 4, 256, 0, stream>>>(xmid, ln2_g, ln2_b, t1, slots, SL_LN2);
  {
    int n4 = NTOK * DMODEL / 4;
    k_quant_act<<<(n4 + 255) / 256, 256, 0, stream>>>(t1, (unsigned*)t1q, n4, slots, SL_LN2);
  }
  k_gemm<2><<<dim3(MMLP / 128, NTOK / 128), 256, 0, stream>>>(
      t1q, w1T, b1, nullptr, nullptr, h1, slots, SL_LN2, SL_W1, slots, SL_GELU,
      NTOK, MMLP, DMODEL);
  {
    int n4 = NTOK * MMLP / 4;
    k_quant_bf16_i8<<<(n4 + 255) / 256, 256, 0, stream>>>(h1, (unsigned*)h1q, n4, slots, SL_GELU);
  }
  k_gemm<1><<<dim3(DMODEL / 128, NTOK / 128), 256, 0, stream>>>(
      h1q, w2T, b2, xmid, outp, nullptr, slots, SL_GELU, SL_W2, nullptr, 0,
      NTOK, DMODEL, MMLP);
}